// Round 1
// baseline (2306.296 us; speedup 1.0000x reference)
//
#include <hip/hip_runtime.h>

#define NN 100000
#define EE 1600000
#define NG 64
#define NCH 98  // ceil(NN/1024)

// fold-area float offsets
#define OFF_WS0 0
#define OFF_WD0 128
#define OFF_CS0 256
#define OFF_CD0 258
#define OFF_U1  260
#define OFF_C1  324
#define OFF_WS1 512
#define OFF_WD1 768
#define OFF_CS1 1024
#define OFF_CD1 1026
#define FOLD_FLOATS 4096

// ---------------- fold: precompute a_s/a_d/a_e-contracted weight vectors ----------------
__global__ void fold_k(const float* __restrict__ Wn0, const float* __restrict__ bn0,
                       const float* __restrict__ as0, const float* __restrict__ ad0,
                       const float* __restrict__ We1, const float* __restrict__ be1,
                       const float* __restrict__ ae1,
                       const float* __restrict__ Wn1, const float* __restrict__ bn1,
                       const float* __restrict__ as1, const float* __restrict__ ad1,
                       float* __restrict__ fold) {
  int t = threadIdx.x;  // 256
  for (int i = t; i < 128; i += 256) {        // ws0/wd0: Wn0[2,64,32] . a[2,32]
    int h = i >> 6, d = i & 63;
    float s = 0.f, sd = 0.f;
    for (int k = 0; k < 32; ++k) {
      float w = Wn0[h*2048 + d*32 + k];
      s  += w * as0[h*32 + k];
      sd += w * ad0[h*32 + k];
    }
    fold[OFF_WS0 + i] = s; fold[OFF_WD0 + i] = sd;
  }
  for (int i = t; i < 64; i += 256) {         // u1: We1[2,32,16] . ae1[2,16]
    int h = i >> 5, d = i & 31;
    float s = 0.f;
    for (int k = 0; k < 16; ++k) s += We1[h*512 + d*16 + k] * ae1[h*16 + k];
    fold[OFF_U1 + i] = s;
  }
  if (t < 256) {                              // ws1/wd1: Wn1[2,128,32] . a[2,32]
    int i = t, h = i >> 7, d = i & 127;
    float s = 0.f, sd = 0.f;
    for (int k = 0; k < 32; ++k) {
      float w = Wn1[h*4096 + d*32 + k];
      s  += w * as1[h*32 + k];
      sd += w * ad1[h*32 + k];
    }
    fold[OFF_WS1 + i] = s; fold[OFF_WD1 + i] = sd;
  }
  if (t < 2) {
    float cs = 0.f, cd = 0.f;
    for (int k = 0; k < 32; ++k) { cs += bn0[t*32+k]*as0[t*32+k]; cd += bn0[t*32+k]*ad0[t*32+k]; }
    fold[OFF_CS0 + t] = cs; fold[OFF_CD0 + t] = cd;
    float c1 = 0.f;
    for (int k = 0; k < 16; ++k) c1 += ae1[t*16+k]*be1[t*16+k];
    fold[OFF_C1 + t] = c1;
    float cs1 = 0.f, cd1 = 0.f;
    for (int k = 0; k < 32; ++k) { cs1 += bn1[t*32+k]*as1[t*32+k]; cd1 += bn1[t*32+k]*ad1[t*32+k]; }
    fold[OFF_CS1 + t] = cs1; fold[OFF_CD1 + t] = cd1;
  }
}

// ---------------- CSR build ----------------
__global__ void count_k(const int* __restrict__ dst, int* __restrict__ cnt) {
  int e = blockIdx.x*256 + threadIdx.x;
  if (e < EE) atomicAdd(&cnt[dst[e]], 1);
}

__global__ __launch_bounds__(1024) void scan1_k(const int* __restrict__ cnt, int* __restrict__ partial) {
  int tid = threadIdx.x, lane = tid & 63, w = tid >> 6;
  int i = blockIdx.x*1024 + tid;
  int v = (i < NN) ? cnt[i] : 0;
  #pragma unroll
  for (int d = 32; d > 0; d >>= 1) v += __shfl_down(v, d);
  __shared__ int wsum[16];
  if (lane == 0) wsum[w] = v;
  __syncthreads();
  if (tid == 0) { int s = 0; for (int q = 0; q < 16; ++q) s += wsum[q]; partial[blockIdx.x] = s; }
}

__global__ void scan2_k(int* __restrict__ partial, int* __restrict__ off) {  // <<<1,1>>>
  int s = 0;
  for (int b = 0; b < NCH; ++b) { int t = partial[b]; partial[b] = s; s += t; }
  off[NN] = s;
}

__global__ __launch_bounds__(1024) void scan3_k(const int* __restrict__ cnt, const int* __restrict__ pbase,
                                                int* __restrict__ off, int* __restrict__ cursor) {
  int tid = threadIdx.x, lane = tid & 63, w = tid >> 6;
  int i = blockIdx.x*1024 + tid;
  int v = (i < NN) ? cnt[i] : 0;
  int x = v;
  #pragma unroll
  for (int d = 1; d < 64; d <<= 1) { int t = __shfl_up(x, d); if (lane >= d) x += t; }
  __shared__ int wsum[16], wbase[16];
  if (lane == 63) wsum[w] = x;
  __syncthreads();
  if (tid == 0) { int s = 0; for (int q = 0; q < 16; ++q) { wbase[q] = s; s += wsum[q]; } }
  __syncthreads();
  int excl = pbase[blockIdx.x] + wbase[w] + x - v;
  if (i < NN) { off[i] = excl; cursor[i] = excl; }
}

__global__ void scatter_k(const int* __restrict__ dst, int* __restrict__ cursor, int* __restrict__ eid) {
  int e = blockIdx.x*256 + threadIdx.x;
  if (e < EE) { int p = atomicAdd(&cursor[dst[e]], 1); eid[p] = e; }
}

// ---------------- layer-0 node pass: v0 = xn@Wv0+bv0, zs0/zd0 scalars ----------------
__global__ __launch_bounds__(128) void node0_k(const float* __restrict__ nt, const float* __restrict__ nl,
                                               const float* __restrict__ Wv0, const float* __restrict__ bv0,
                                               const float* __restrict__ fold,
                                               float* __restrict__ v0, float* __restrict__ zs0, float* __restrict__ zd0) {
  int n = blockIdx.x, tid = threadIdx.x;
  __shared__ float xn[64];
  if (tid < 64) xn[tid] = (tid < 14) ? nt[n*14 + tid] : nl[n*50 + tid - 14];
  __syncthreads();
  int h = tid >> 6, k = tid & 63;
  float acc = bv0[tid];
  const float* wp = Wv0 + h*4096 + k;
  #pragma unroll 8
  for (int d = 0; d < 64; ++d) acc += xn[d] * wp[d*64];
  v0[n*128 + tid] = acc;
  if (tid < 64) {
    float x = xn[tid];
    float p0 = x * fold[OFF_WS0 + tid];
    float p1 = x * fold[OFF_WS0 + 64 + tid];
    float p2 = x * fold[OFF_WD0 + tid];
    float p3 = x * fold[OFF_WD0 + 64 + tid];
    #pragma unroll
    for (int o = 32; o > 0; o >>= 1) {
      p0 += __shfl_down(p0, o); p1 += __shfl_down(p1, o);
      p2 += __shfl_down(p2, o); p3 += __shfl_down(p3, o);
    }
    if (tid == 0) {
      zs0[n*2]   = p0 + fold[OFF_CS0];
      zs0[n*2+1] = p1 + fold[OFF_CS0+1];
      zd0[n*2]   = p2 + fold[OFF_CD0];
      zd0[n*2+1] = p3 + fold[OFF_CD0+1];
    }
  }
}

// ---------------- layer-0 edge pass: ze0 in regs -> s0 logits + layer-1 edge term ----------------
__global__ __launch_bounds__(256) void edge0_k(const float* __restrict__ xe,
                                               const int* __restrict__ src, const int* __restrict__ dst,
                                               const float* __restrict__ We0, const float* __restrict__ be0,
                                               const float* __restrict__ ae0, const float* __restrict__ ab0,
                                               const float* __restrict__ fold,
                                               const float* __restrict__ zs0, const float* __restrict__ zd0,
                                               float* __restrict__ sb, float* __restrict__ et1) {
  __shared__ float W[1024], AE[32], BE[32], U1[64];
  int tid = threadIdx.x;
  for (int i = tid; i < 1024; i += 256) W[i] = We0[i];
  if (tid < 32) { AE[tid] = ae0[tid]; BE[tid] = be0[tid]; }
  if (tid < 64) U1[tid] = fold[OFF_U1 + tid];
  __syncthreads();
  int e = blockIdx.x*256 + tid;
  if (e >= EE) return;
  float x[32];
  const float4* xp = reinterpret_cast<const float4*>(xe + (size_t)e*32);
  #pragma unroll
  for (int q = 0; q < 8; ++q) {
    float4 f = xp[q];
    x[q*4] = f.x; x[q*4+1] = f.y; x[q*4+2] = f.z; x[q*4+3] = f.w;
  }
  float s0 = 0.f, s1 = 0.f, etA = 0.f, etB = 0.f;
  #pragma unroll
  for (int o = 0; o < 32; ++o) {
    float acc = BE[o];
    const float* wc = &W[(o >> 4)*512 + (o & 15)];
    #pragma unroll
    for (int d = 0; d < 32; ++d) acc += x[d] * wc[d*16];
    if (o < 16) s0 += AE[o]*acc; else s1 += AE[o]*acc;
    float lz = acc >= 0.f ? acc : 0.01f*acc;   // inter-layer leaky on xe1
    etA += lz * U1[o];
    etB += lz * U1[32 + o];
  }
  int sn = src[e], dn = dst[e];
  float l0 = zs0[sn*2]   + s0 + zd0[dn*2]   + ab0[0];
  float l1 = zs0[sn*2+1] + s1 + zd0[dn*2+1] + ab0[1];
  sb[e*2]   = l0 >= 0.f ? l0 : 0.2f*l0;
  sb[e*2+1] = l1 >= 0.f ? l1 : 0.2f*l1;
  et1[e*2]   = etA + fold[OFF_C1];
  et1[e*2+1] = etB + fold[OFF_C1+1];
}

// ---------------- layer-0 aggregate (online softmax) fused with layer-1 node pass ----------------
__global__ __launch_bounds__(256) void agg0_k(const int* __restrict__ off, const int* __restrict__ eid,
                                              const int* __restrict__ src,
                                              const float* __restrict__ sb, const float* __restrict__ v0,
                                              const float* __restrict__ Wv1, const float* __restrict__ bv1,
                                              const float* __restrict__ fold,
                                              float* __restrict__ v1, float* __restrict__ zs1, float* __restrict__ zd1) {
  int tid = threadIdx.x, w = tid >> 6, lane = tid & 63;
  int n = blockIdx.x*4 + w;
  __shared__ float xsh[4][128];
  float x0 = 0.f, x1 = 0.f;
  if (n < NN) {
    int st = off[n], en = off[n+1];
    float m0 = -1e30f, m1 = -1e30f, d0 = 0.f, d1 = 0.f, a0 = 0.f, a1 = 0.f;
    for (int i = st; i < en; ++i) {
      int e = eid[i];
      int sn = src[e];
      float s0 = sb[e*2], s1 = sb[e*2+1];
      float vA = v0[sn*128 + lane];
      float vB = v0[sn*128 + 64 + lane];
      float nm0 = fmaxf(m0, s0);
      float sc0 = __expf(m0 - nm0);
      float e0  = __expf(s0 - nm0);
      d0 = d0*sc0 + e0; a0 = a0*sc0 + e0*vA; m0 = nm0;
      float nm1 = fmaxf(m1, s1);
      float sc1 = __expf(m1 - nm1);
      float e1  = __expf(s1 - nm1);
      d1 = d1*sc1 + e1; a1 = a1*sc1 + e1*vB; m1 = nm1;
    }
    float h0 = a0 / (d0 + 1e-9f);
    float h1 = a1 / (d1 + 1e-9f);
    x0 = h0 >= 0.f ? h0 : 0.01f*h0;   // inter-layer leaky
    x1 = h1 >= 0.f ? h1 : 0.01f*h1;
    xsh[w][lane] = x0; xsh[w][64 + lane] = x1;
  }
  __syncthreads();
  if (n < NN) {
    float accA = bv1[lane], accB = bv1[64 + lane];
    #pragma unroll 8
    for (int d = 0; d < 128; ++d) {
      float xd = xsh[w][d];
      accA += xd * Wv1[d*64 + lane];
      accB += xd * Wv1[8192 + d*64 + lane];
    }
    v1[n*128 + lane] = accA;
    v1[n*128 + 64 + lane] = accB;
    float p0 = x0*fold[OFF_WS1 + lane]       + x1*fold[OFF_WS1 + 64 + lane];
    float p1 = x0*fold[OFF_WS1 + 128 + lane] + x1*fold[OFF_WS1 + 192 + lane];
    float p2 = x0*fold[OFF_WD1 + lane]       + x1*fold[OFF_WD1 + 64 + lane];
    float p3 = x0*fold[OFF_WD1 + 128 + lane] + x1*fold[OFF_WD1 + 192 + lane];
    #pragma unroll
    for (int o = 32; o > 0; o >>= 1) {
      p0 += __shfl_down(p0, o); p1 += __shfl_down(p1, o);
      p2 += __shfl_down(p2, o); p3 += __shfl_down(p3, o);
    }
    if (lane == 0) {
      zs1[n*2]   = p0 + fold[OFF_CS1];
      zs1[n*2+1] = p1 + fold[OFF_CS1+1];
      zd1[n*2]   = p2 + fold[OFF_CD1];
      zd1[n*2+1] = p3 + fold[OFF_CD1+1];
    }
  }
}

// ---------------- layer-1 edge logits ----------------
__global__ __launch_bounds__(256) void edge1_k(const int* __restrict__ src, const int* __restrict__ dst,
                                               const float* __restrict__ zs1, const float* __restrict__ zd1,
                                               const float* __restrict__ et1, const float* __restrict__ ab1,
                                               float* __restrict__ sb) {
  int e = blockIdx.x*256 + threadIdx.x;
  if (e >= EE) return;
  int sn = src[e], dn = dst[e];
  float l0 = zs1[sn*2]   + et1[e*2]   + zd1[dn*2]   + ab1[0];
  float l1 = zs1[sn*2+1] + et1[e*2+1] + zd1[dn*2+1] + ab1[1];
  sb[e*2]   = l0 >= 0.f ? l0 : 0.2f*l0;
  sb[e*2+1] = l1 >= 0.f ? l1 : 0.2f*l1;
}

__global__ void outinit_k(const float* __restrict__ fcb, float* __restrict__ out) {
  int i = threadIdx.x;  // 128
  out[i] = fcb[i & 1];
}

// ---------------- layer-1 aggregate fused with final FC + graph segment-sum ----------------
__global__ __launch_bounds__(256) void agg1_k(const int* __restrict__ off, const int* __restrict__ eid,
                                              const int* __restrict__ src,
                                              const float* __restrict__ sb, const float* __restrict__ v1,
                                              const int* __restrict__ gid, const float* __restrict__ fcW,
                                              float* __restrict__ out) {
  int tid = threadIdx.x, w = tid >> 6, lane = tid & 63;
  int n = blockIdx.x*4 + w;
  if (n >= NN) return;
  int st = off[n], en = off[n+1];
  float m0 = -1e30f, m1 = -1e30f, d0 = 0.f, d1 = 0.f, a0 = 0.f, a1 = 0.f;
  for (int i = st; i < en; ++i) {
    int e = eid[i];
    int sn = src[e];
    float s0 = sb[e*2], s1 = sb[e*2+1];
    float vA = v1[sn*128 + lane];
    float vB = v1[sn*128 + 64 + lane];
    float nm0 = fmaxf(m0, s0);
    float sc0 = __expf(m0 - nm0);
    float e0  = __expf(s0 - nm0);
    d0 = d0*sc0 + e0; a0 = a0*sc0 + e0*vA; m0 = nm0;
    float nm1 = fmaxf(m1, s1);
    float sc1 = __expf(m1 - nm1);
    float e1  = __expf(s1 - nm1);
    d1 = d1*sc1 + e1; a1 = a1*sc1 + e1*vB; m1 = nm1;
  }
  float h0 = a0 / (d0 + 1e-9f);   // final layer: NO leaky
  float h1 = a1 / (d1 + 1e-9f);
  float p0 = h0*fcW[lane*2]     + h1*fcW[(64+lane)*2];
  float p1 = h0*fcW[lane*2 + 1] + h1*fcW[(64+lane)*2 + 1];
  #pragma unroll
  for (int o = 32; o > 0; o >>= 1) {
    p0 += __shfl_down(p0, o);
    p1 += __shfl_down(p1, o);
  }
  if (lane == 0) {
    int g = gid[n];
    atomicAdd(&out[g*2],     p0);
    atomicAdd(&out[g*2 + 1], p1);
  }
}

extern "C" void kernel_launch(void* const* d_in, const int* in_sizes, int n_in,
                              void* d_out, int out_size, void* d_ws, size_t ws_size,
                              hipStream_t stream) {
  const float* nt  = (const float*)d_in[0];
  const float* nl  = (const float*)d_in[1];
  const float* xe  = (const float*)d_in[2];
  const int*   src = (const int*)d_in[3];
  const int*   dst = (const int*)d_in[4];
  const int*   gid = (const int*)d_in[5];
  const float* Wn0 = (const float*)d_in[6],  *bn0 = (const float*)d_in[7];
  const float* Wv0 = (const float*)d_in[8],  *bv0 = (const float*)d_in[9];
  const float* We0 = (const float*)d_in[10], *be0 = (const float*)d_in[11];
  const float* as0 = (const float*)d_in[12], *ae0 = (const float*)d_in[13];
  const float* ad0 = (const float*)d_in[14], *ab0 = (const float*)d_in[15];
  const float* Wn1 = (const float*)d_in[16], *bn1 = (const float*)d_in[17];
  const float* Wv1 = (const float*)d_in[18], *bv1 = (const float*)d_in[19];
  const float* We1 = (const float*)d_in[20], *be1 = (const float*)d_in[21];
  const float* as1 = (const float*)d_in[22], *ae1 = (const float*)d_in[23];
  const float* ad1 = (const float*)d_in[24], *ab1 = (const float*)d_in[25];
  const float* fcW = (const float*)d_in[26], *fcb = (const float*)d_in[27];
  float* out = (float*)d_out;

  // workspace layout (floats then ints); total ~137 MB
  float* fold = (float*)d_ws;
  float* zs   = fold + FOLD_FLOATS;          // N*2 (layer0 then reused for layer1)
  float* zd   = zs + (size_t)NN*2;           // N*2
  float* v0   = zd + (size_t)NN*2;           // N*128
  float* v1   = v0 + (size_t)NN*128;         // N*128
  float* et1  = v1 + (size_t)NN*128;         // E*2
  float* sb   = et1 + (size_t)EE*2;          // E*2 (s0 then reused for s1)
  int* cnt    = (int*)(sb + (size_t)EE*2);   // N
  int* off    = cnt + NN;                    // N+1
  int* cursor = off + NN + 1;                // N
  int* eid    = cursor + NN;                 // E
  int* part   = eid + EE;                    // NCH

  hipMemsetAsync(cnt, 0, NN*sizeof(int), stream);
  fold_k<<<1, 256, 0, stream>>>(Wn0, bn0, as0, ad0, We1, be1, ae1, Wn1, bn1, as1, ad1, fold);
  count_k<<<EE/256, 256, 0, stream>>>(dst, cnt);
  scan1_k<<<NCH, 1024, 0, stream>>>(cnt, part);
  scan2_k<<<1, 1, 0, stream>>>(part, off);
  scan3_k<<<NCH, 1024, 0, stream>>>(cnt, part, off, cursor);
  scatter_k<<<EE/256, 256, 0, stream>>>(dst, cursor, eid);
  node0_k<<<NN, 128, 0, stream>>>(nt, nl, Wv0, bv0, fold, v0, zs, zd);
  edge0_k<<<EE/256, 256, 0, stream>>>(xe, src, dst, We0, be0, ae0, ab0, fold, zs, zd, sb, et1);
  agg0_k<<<NN/4, 256, 0, stream>>>(off, eid, src, sb, v0, Wv1, bv1, fold, v1, zs, zd);
  edge1_k<<<EE/256, 256, 0, stream>>>(src, dst, zs, zd, et1, ab1, sb);
  outinit_k<<<1, 128, 0, stream>>>(fcb, out);
  agg1_k<<<NN/4, 256, 0, stream>>>(off, eid, src, sb, v1, gid, fcW, out);
}

// Round 2
// 2036.925 us; speedup vs baseline: 1.1322x; 1.1322x over previous
//
#include <hip/hip_runtime.h>

#define NN 100000
#define EE 1600000
#define NG 64
#define NCH 98  // ceil(NN/1024)

// fold-area float offsets
#define OFF_WS0 0
#define OFF_WD0 128
#define OFF_CS0 256
#define OFF_CD0 258
#define OFF_U1  260
#define OFF_C1  324
#define OFF_WS1 512
#define OFF_WD1 768
#define OFF_CS1 1024
#define OFF_CD1 1026
#define FOLD_FLOATS 4096

__device__ __forceinline__ unsigned encm(float f) {
  unsigned u = __float_as_uint(f);
  return (u & 0x80000000u) ? ~u : (u | 0x80000000u);
}
__device__ __forceinline__ float decm(unsigned u) {
  return (u & 0x80000000u) ? __uint_as_float(u & 0x7FFFFFFFu) : __uint_as_float(~u);
}

// ---------------- fold: precompute a_s/a_d/a_e-contracted weight vectors ----------------
__global__ void fold_k(const float* __restrict__ Wn0, const float* __restrict__ bn0,
                       const float* __restrict__ as0, const float* __restrict__ ad0,
                       const float* __restrict__ We1, const float* __restrict__ be1,
                       const float* __restrict__ ae1,
                       const float* __restrict__ Wn1, const float* __restrict__ bn1,
                       const float* __restrict__ as1, const float* __restrict__ ad1,
                       float* __restrict__ fold) {
  int t = threadIdx.x;  // 256
  for (int i = t; i < 128; i += 256) {        // ws0/wd0: Wn0[2,64,32] . a[2,32]
    int h = i >> 6, d = i & 63;
    float s = 0.f, sd = 0.f;
    for (int k = 0; k < 32; ++k) {
      float w = Wn0[h*2048 + d*32 + k];
      s  += w * as0[h*32 + k];
      sd += w * ad0[h*32 + k];
    }
    fold[OFF_WS0 + i] = s; fold[OFF_WD0 + i] = sd;
  }
  for (int i = t; i < 64; i += 256) {         // u1: We1[2,32,16] . ae1[2,16]
    int h = i >> 5, d = i & 31;
    float s = 0.f;
    for (int k = 0; k < 16; ++k) s += We1[h*512 + d*16 + k] * ae1[h*16 + k];
    fold[OFF_U1 + i] = s;
  }
  if (t < 256) {                              // ws1/wd1: Wn1[2,128,32] . a[2,32]
    int i = t, h = i >> 7, d = i & 127;
    float s = 0.f, sd = 0.f;
    for (int k = 0; k < 32; ++k) {
      float w = Wn1[h*4096 + d*32 + k];
      s  += w * as1[h*32 + k];
      sd += w * ad1[h*32 + k];
    }
    fold[OFF_WS1 + i] = s; fold[OFF_WD1 + i] = sd;
  }
  if (t < 2) {
    float cs = 0.f, cd = 0.f;
    for (int k = 0; k < 32; ++k) { cs += bn0[t*32+k]*as0[t*32+k]; cd += bn0[t*32+k]*ad0[t*32+k]; }
    fold[OFF_CS0 + t] = cs; fold[OFF_CD0 + t] = cd;
    float c1 = 0.f;
    for (int k = 0; k < 16; ++k) c1 += ae1[t*16+k]*be1[t*16+k];
    fold[OFF_C1 + t] = c1;
    float cs1 = 0.f, cd1 = 0.f;
    for (int k = 0; k < 32; ++k) { cs1 += bn1[t*32+k]*as1[t*32+k]; cd1 += bn1[t*32+k]*ad1[t*32+k]; }
    fold[OFF_CS1 + t] = cs1; fold[OFF_CD1 + t] = cd1;
  }
}

// ---------------- CSR build ----------------
__global__ void count_k(const int* __restrict__ dst, int* __restrict__ cnt) {
  int e = blockIdx.x*256 + threadIdx.x;
  if (e < EE) atomicAdd(&cnt[dst[e]], 1);
}

__global__ __launch_bounds__(1024) void scan1_k(const int* __restrict__ cnt, int* __restrict__ partial) {
  int tid = threadIdx.x, lane = tid & 63, w = tid >> 6;
  int i = blockIdx.x*1024 + tid;
  int v = (i < NN) ? cnt[i] : 0;
  #pragma unroll
  for (int d = 32; d > 0; d >>= 1) v += __shfl_down(v, d);
  __shared__ int wsum[16];
  if (lane == 0) wsum[w] = v;
  __syncthreads();
  if (tid == 0) { int s = 0; for (int q = 0; q < 16; ++q) s += wsum[q]; partial[blockIdx.x] = s; }
}

__global__ void scan2_k(int* __restrict__ partial, int* __restrict__ off) {  // <<<1,1>>>
  int s = 0;
  for (int b = 0; b < NCH; ++b) { int t = partial[b]; partial[b] = s; s += t; }
  off[NN] = s;
}

__global__ __launch_bounds__(1024) void scan3_k(const int* __restrict__ cnt, const int* __restrict__ pbase,
                                                int* __restrict__ off, int* __restrict__ cursor) {
  int tid = threadIdx.x, lane = tid & 63, w = tid >> 6;
  int i = blockIdx.x*1024 + tid;
  int v = (i < NN) ? cnt[i] : 0;
  int x = v;
  #pragma unroll
  for (int d = 1; d < 64; d <<= 1) { int t = __shfl_up(x, d); if (lane >= d) x += t; }
  __shared__ int wsum[16], wbase[16];
  if (lane == 63) wsum[w] = x;
  __syncthreads();
  if (tid == 0) { int s = 0; for (int q = 0; q < 16; ++q) { wbase[q] = s; s += wsum[q]; } }
  __syncthreads();
  int excl = pbase[blockIdx.x] + wbase[w] + x - v;
  if (i < NN) { off[i] = excl; cursor[i] = excl; }
}

__global__ void scatter_k(const int* __restrict__ dst, int* __restrict__ cursor,
                          int* __restrict__ pos, int* __restrict__ dstp) {
  int e = blockIdx.x*256 + threadIdx.x;
  if (e < EE) {
    int dn = dst[e];
    int p = atomicAdd(&cursor[dn], 1);
    pos[e] = p; dstp[p] = dn;
  }
}

// ---------------- layer-0 node pass: v0 = xn@Wv0+bv0, zs0/zd0 scalars ----------------
__global__ __launch_bounds__(128) void node0_k(const float* __restrict__ nt, const float* __restrict__ nl,
                                               const float* __restrict__ Wv0, const float* __restrict__ bv0,
                                               const float* __restrict__ fold,
                                               float* __restrict__ v0, float* __restrict__ zs0, float* __restrict__ zd0) {
  int n = blockIdx.x, tid = threadIdx.x;
  __shared__ float xn[64];
  if (tid < 64) xn[tid] = (tid < 14) ? nt[n*14 + tid] : nl[n*50 + tid - 14];
  __syncthreads();
  int h = tid >> 6, k = tid & 63;
  float acc = bv0[tid];
  const float* wp = Wv0 + h*4096 + k;
  #pragma unroll 8
  for (int d = 0; d < 64; ++d) acc += xn[d] * wp[d*64];
  v0[(size_t)n*128 + tid] = acc;
  if (tid < 64) {
    float x = xn[tid];
    float p0 = x * fold[OFF_WS0 + tid];
    float p1 = x * fold[OFF_WS0 + 64 + tid];
    float p2 = x * fold[OFF_WD0 + tid];
    float p3 = x * fold[OFF_WD0 + 64 + tid];
    #pragma unroll
    for (int o = 32; o > 0; o >>= 1) {
      p0 += __shfl_down(p0, o); p1 += __shfl_down(p1, o);
      p2 += __shfl_down(p2, o); p3 += __shfl_down(p3, o);
    }
    if (tid == 0) {
      zs0[n*2]   = p0 + fold[OFF_CS0];
      zs0[n*2+1] = p1 + fold[OFF_CS0+1];
      zd0[n*2]   = p2 + fold[OFF_CD0];
      zd0[n*2+1] = p3 + fold[OFF_CD0+1];
    }
  }
}

// ---------------- layer-0 edge pass: logits into ebuf[pos[e]], layer-1 edge term ----------------
__global__ __launch_bounds__(256) void edge0_k(const float* __restrict__ xe,
                                               const int* __restrict__ src, const int* __restrict__ dst,
                                               const float* __restrict__ We0, const float* __restrict__ be0,
                                               const float* __restrict__ ae0, const float* __restrict__ ab0,
                                               const float* __restrict__ fold,
                                               const float* __restrict__ zs0, const float* __restrict__ zd0,
                                               const int* __restrict__ pos,
                                               float4* __restrict__ ebuf, float* __restrict__ et1p) {
  __shared__ float W[1024], AE[32], BE[32], U1[64];
  int tid = threadIdx.x;
  for (int i = tid; i < 1024; i += 256) W[i] = We0[i];
  if (tid < 32) { AE[tid] = ae0[tid]; BE[tid] = be0[tid]; }
  if (tid < 64) U1[tid] = fold[OFF_U1 + tid];
  __syncthreads();
  int e = blockIdx.x*256 + tid;
  if (e >= EE) return;
  float x[32];
  const float4* xp = reinterpret_cast<const float4*>(xe + (size_t)e*32);
  #pragma unroll
  for (int q = 0; q < 8; ++q) {
    float4 f = xp[q];
    x[q*4] = f.x; x[q*4+1] = f.y; x[q*4+2] = f.z; x[q*4+3] = f.w;
  }
  float s0 = 0.f, s1 = 0.f, etA = 0.f, etB = 0.f;
  #pragma unroll
  for (int o = 0; o < 32; ++o) {
    float acc = BE[o];
    const float* wc = &W[(o >> 4)*512 + (o & 15)];
    #pragma unroll
    for (int d = 0; d < 32; ++d) acc += x[d] * wc[d*16];
    if (o < 16) s0 += AE[o]*acc; else s1 += AE[o]*acc;
    float lz = acc >= 0.f ? acc : 0.01f*acc;   // inter-layer leaky on xe1
    etA += lz * U1[o];
    etB += lz * U1[32 + o];
  }
  int sn = src[e], dn = dst[e];
  float l0 = zs0[sn*2]   + s0 + zd0[dn*2]   + ab0[0];
  float l1 = zs0[sn*2+1] + s1 + zd0[dn*2+1] + ab0[1];
  l0 = l0 >= 0.f ? l0 : 0.2f*l0;
  l1 = l1 >= 0.f ? l1 : 0.2f*l1;
  int p = pos[e];
  ebuf[p] = make_float4(__int_as_float(sn), l0, l1, 0.f);
  *reinterpret_cast<float2*>(et1p + (size_t)p*2) =
      make_float2(etA + fold[OFF_C1], etB + fold[OFF_C1+1]);
}

// ---------------- per-node max of logits (edge-parallel, segmented wave reduce) ----------------
__global__ __launch_bounds__(256) void kmax_k(const float4* __restrict__ ebuf, const int* __restrict__ dstp,
                                              unsigned* __restrict__ menc) {
  int i = blockIdx.x*256 + threadIdx.x;
  int lane = threadIdx.x & 63;
  bool okv = i < EE;
  float4 eb = okv ? ebuf[i] : make_float4(0.f, 0.f, 0.f, 0.f);
  int dn = okv ? dstp[i] : -1;
  unsigned e0 = okv ? encm(eb.y) : 0u;
  unsigned e1 = okv ? encm(eb.z) : 0u;
  #pragma unroll
  for (int o = 1; o < 64; o <<= 1) {
    int pdn = __shfl_down(dn, o);
    unsigned q0 = __shfl_down(e0, o);
    unsigned q1 = __shfl_down(e1, o);
    if (pdn == dn) { e0 = max(e0, q0); e1 = max(e1, q1); }
  }
  int prev = __shfl_up(dn, 1);
  if (okv && (lane == 0 || prev != dn)) {
    atomicMax(&menc[(size_t)dn*2],   e0);
    atomicMax(&menc[(size_t)dn*2+1], e1);
  }
}

// ---------------- layer-0 aggregate (batched, no rescale) fused with layer-1 node pass ----------------
__global__ __launch_bounds__(256) void agg0_k(const int* __restrict__ off,
                                              const float4* __restrict__ ebuf,
                                              const unsigned* __restrict__ menc,
                                              const float* __restrict__ v0,
                                              const float* __restrict__ Wv1, const float* __restrict__ bv1,
                                              const float* __restrict__ fold,
                                              float* __restrict__ v1, float* __restrict__ zs1, float* __restrict__ zd1) {
  int tid = threadIdx.x, w = tid >> 6, lane = tid & 63;
  int n = blockIdx.x*4 + w;
  __shared__ float xsh[4][128];
  float xa = 0.f, xb = 0.f;
  if (n < NN) {
    int st = off[n], en = off[n+1];
    float m0 = decm(menc[n*2]), m1 = decm(menc[n*2+1]);
    float d0 = 0.f, d1 = 0.f, aa = 0.f, ab = 0.f;
    for (int i = st; i < en; i += 8) {
      int jj[8]; float4 eb[8];
      #pragma unroll
      for (int q = 0; q < 8; ++q) jj[q] = (i+q < en) ? i+q : st;
      #pragma unroll
      for (int q = 0; q < 8; ++q) eb[q] = ebuf[jj[q]];
      #pragma unroll
      for (int q = 0; q < 8; ++q) {
        int sn = __float_as_int(eb[q].x);
        float2 vv = *reinterpret_cast<const float2*>(v0 + (size_t)sn*128 + lane*2);
        bool okq = (i+q) < en;
        float e0 = okq ? __expf(eb[q].y - m0) : 0.f;
        float e1 = okq ? __expf(eb[q].z - m1) : 0.f;
        float es = (lane < 32) ? e0 : e1;
        d0 += e0; d1 += e1;
        aa = fmaf(es, vv.x, aa); ab = fmaf(es, vv.y, ab);
      }
    }
    float den = ((lane < 32) ? d0 : d1) + 1e-9f;
    float ha = aa/den, hb = ab/den;
    xa = ha >= 0.f ? ha : 0.01f*ha;   // inter-layer leaky
    xb = hb >= 0.f ? hb : 0.01f*hb;
    xsh[w][lane*2] = xa; xsh[w][lane*2+1] = xb;
  }
  __syncthreads();
  if (n < NN) {
    float accA = bv1[lane], accB = bv1[64 + lane];
    #pragma unroll 8
    for (int d = 0; d < 128; ++d) {
      float xd = xsh[w][d];
      accA = fmaf(xd, Wv1[d*64 + lane], accA);
      accB = fmaf(xd, Wv1[8192 + d*64 + lane], accB);
    }
    v1[(size_t)n*128 + lane] = accA;
    v1[(size_t)n*128 + 64 + lane] = accB;
    int l2 = lane*2;
    float p0 = xa*fold[OFF_WS1+l2]       + xb*fold[OFF_WS1+l2+1];
    float p1 = xa*fold[OFF_WS1+128+l2]   + xb*fold[OFF_WS1+128+l2+1];
    float p2 = xa*fold[OFF_WD1+l2]       + xb*fold[OFF_WD1+l2+1];
    float p3 = xa*fold[OFF_WD1+128+l2]   + xb*fold[OFF_WD1+128+l2+1];
    #pragma unroll
    for (int o = 32; o > 0; o >>= 1) {
      p0 += __shfl_down(p0, o); p1 += __shfl_down(p1, o);
      p2 += __shfl_down(p2, o); p3 += __shfl_down(p3, o);
    }
    if (lane == 0) {
      zs1[n*2]   = p0 + fold[OFF_CS1];
      zs1[n*2+1] = p1 + fold[OFF_CS1+1];
      zd1[n*2]   = p2 + fold[OFF_CD1];
      zd1[n*2+1] = p3 + fold[OFF_CD1+1];
    }
  }
}

// ---------------- layer-1 edge logits (CSR-position-parallel) ----------------
__global__ __launch_bounds__(256) void edge1_k(float4* __restrict__ ebuf, const int* __restrict__ dstp,
                                               const float* __restrict__ zs1, const float* __restrict__ zd1,
                                               const float* __restrict__ et1p, const float* __restrict__ ab1) {
  int i = blockIdx.x*256 + threadIdx.x;
  if (i >= EE) return;
  float4 eb = ebuf[i];
  int sn = __float_as_int(eb.x);
  int dn = dstp[i];
  float2 et = *reinterpret_cast<const float2*>(et1p + (size_t)i*2);
  float l0 = zs1[sn*2]   + et.x + zd1[dn*2]   + ab1[0];
  float l1 = zs1[sn*2+1] + et.y + zd1[dn*2+1] + ab1[1];
  eb.y = l0 >= 0.f ? l0 : 0.2f*l0;
  eb.z = l1 >= 0.f ? l1 : 0.2f*l1;
  ebuf[i] = eb;
}

__global__ void outinit_k(const float* __restrict__ fcb, float* __restrict__ out) {
  int i = threadIdx.x;  // 128
  out[i] = fcb[i & 1];
}

// ---------------- layer-1 aggregate fused with final FC + graph segment-sum ----------------
__global__ __launch_bounds__(256) void agg1_k(const int* __restrict__ off,
                                              const float4* __restrict__ ebuf,
                                              const unsigned* __restrict__ menc,
                                              const float* __restrict__ v1,
                                              const int* __restrict__ gid, const float* __restrict__ fcW,
                                              float* __restrict__ out) {
  int tid = threadIdx.x, w = tid >> 6, lane = tid & 63;
  int n = blockIdx.x*4 + w;
  if (n >= NN) return;
  int st = off[n], en = off[n+1];
  float m0 = decm(menc[n*2]), m1 = decm(menc[n*2+1]);
  float d0 = 0.f, d1 = 0.f, aa = 0.f, ab = 0.f;
  for (int i = st; i < en; i += 8) {
    int jj[8]; float4 eb[8];
    #pragma unroll
    for (int q = 0; q < 8; ++q) jj[q] = (i+q < en) ? i+q : st;
    #pragma unroll
    for (int q = 0; q < 8; ++q) eb[q] = ebuf[jj[q]];
    #pragma unroll
    for (int q = 0; q < 8; ++q) {
      int sn = __float_as_int(eb[q].x);
      float2 vv = *reinterpret_cast<const float2*>(v1 + (size_t)sn*128 + lane*2);
      bool okq = (i+q) < en;
      float e0 = okq ? __expf(eb[q].y - m0) : 0.f;
      float e1 = okq ? __expf(eb[q].z - m1) : 0.f;
      float es = (lane < 32) ? e0 : e1;
      d0 += e0; d1 += e1;
      aa = fmaf(es, vv.x, aa); ab = fmaf(es, vv.y, ab);
    }
  }
  float den = ((lane < 32) ? d0 : d1) + 1e-9f;
  float ha = aa/den, hb = ab/den;   // final layer: NO leaky
  int l2 = lane*2;
  float p0 = ha*fcW[l2*2]     + hb*fcW[(l2+1)*2];
  float p1 = ha*fcW[l2*2 + 1] + hb*fcW[(l2+1)*2 + 1];
  #pragma unroll
  for (int o = 32; o > 0; o >>= 1) {
    p0 += __shfl_down(p0, o);
    p1 += __shfl_down(p1, o);
  }
  if (lane == 0) {
    int g = gid[n];
    atomicAdd(&out[g*2],     p0);
    atomicAdd(&out[g*2 + 1], p1);
  }
}

extern "C" void kernel_launch(void* const* d_in, const int* in_sizes, int n_in,
                              void* d_out, int out_size, void* d_ws, size_t ws_size,
                              hipStream_t stream) {
  const float* nt  = (const float*)d_in[0];
  const float* nl  = (const float*)d_in[1];
  const float* xe  = (const float*)d_in[2];
  const int*   src = (const int*)d_in[3];
  const int*   dst = (const int*)d_in[4];
  const int*   gid = (const int*)d_in[5];
  const float* Wn0 = (const float*)d_in[6],  *bn0 = (const float*)d_in[7];
  const float* Wv0 = (const float*)d_in[8],  *bv0 = (const float*)d_in[9];
  const float* We0 = (const float*)d_in[10], *be0 = (const float*)d_in[11];
  const float* as0 = (const float*)d_in[12], *ae0 = (const float*)d_in[13];
  const float* ad0 = (const float*)d_in[14], *ab0 = (const float*)d_in[15];
  const float* Wn1 = (const float*)d_in[16], *bn1 = (const float*)d_in[17];
  const float* Wv1 = (const float*)d_in[18], *bv1 = (const float*)d_in[19];
  const float* We1 = (const float*)d_in[20], *be1 = (const float*)d_in[21];
  const float* ae1 = (const float*)d_in[23];
  const float* as1 = (const float*)d_in[22];
  const float* ad1 = (const float*)d_in[24], *ab1 = (const float*)d_in[25];
  const float* fcW = (const float*)d_in[26], *fcb = (const float*)d_in[27];
  float* out = (float*)d_out;

  // workspace layout (floats, then ints); ~156 MB
  float* fold  = (float*)d_ws;                      // 4096
  float* zs    = fold + FOLD_FLOATS;                // N*2 (layer0 then layer1)
  float* zd    = zs + (size_t)NN*2;                 // N*2
  float* v0    = zd + (size_t)NN*2;                 // N*128
  float* v1    = v0 + (size_t)NN*128;               // N*128
  float* et1p  = v1 + (size_t)NN*128;               // E*2
  float* ebuff = et1p + (size_t)EE*2;               // E*4 (float4 per CSR pos)
  unsigned* menc = (unsigned*)(ebuff + (size_t)EE*4); // N*2
  int* cnt    = (int*)(menc + (size_t)NN*2);        // N
  int* off    = cnt + NN;                           // N+1
  int* cursor = off + NN + 1;                       // N
  int* pos    = cursor + NN;                        // E
  int* dstp   = pos + EE;                           // E
  int* part   = dstp + EE;                          // NCH
  float4* ebuf = (float4*)ebuff;

  hipMemsetAsync(cnt, 0, NN*sizeof(int), stream);
  hipMemsetAsync(menc, 0, (size_t)NN*2*sizeof(unsigned), stream);
  fold_k<<<1, 256, 0, stream>>>(Wn0, bn0, as0, ad0, We1, be1, ae1, Wn1, bn1, as1, ad1, fold);
  count_k<<<EE/256, 256, 0, stream>>>(dst, cnt);
  scan1_k<<<NCH, 1024, 0, stream>>>(cnt, part);
  scan2_k<<<1, 1, 0, stream>>>(part, off);
  scan3_k<<<NCH, 1024, 0, stream>>>(cnt, part, off, cursor);
  scatter_k<<<EE/256, 256, 0, stream>>>(dst, cursor, pos, dstp);
  node0_k<<<NN, 128, 0, stream>>>(nt, nl, Wv0, bv0, fold, v0, zs, zd);
  edge0_k<<<EE/256, 256, 0, stream>>>(xe, src, dst, We0, be0, ae0, ab0, fold, zs, zd, pos, ebuf, et1p);
  kmax_k<<<EE/256, 256, 0, stream>>>(ebuf, dstp, menc);
  agg0_k<<<NN/4, 256, 0, stream>>>(off, ebuf, menc, v0, Wv1, bv1, fold, v1, zs, zd);
  edge1_k<<<EE/256, 256, 0, stream>>>(ebuf, dstp, zs, zd, et1p, ab1);
  hipMemsetAsync(menc, 0, (size_t)NN*2*sizeof(unsigned), stream);
  kmax_k<<<EE/256, 256, 0, stream>>>(ebuf, dstp, menc);
  outinit_k<<<1, 128, 0, stream>>>(fcb, out);
  agg1_k<<<NN/4, 256, 0, stream>>>(off, ebuf, menc, v1, gid, fcW, out);
}

// Round 3
// 1082.782 us; speedup vs baseline: 2.1300x; 1.8812x over previous
//
#include <hip/hip_runtime.h>

#define NN 100000
#define EE 1600000
#define NG 64
#define NCH 98  // ceil(NN/1024)

// fold-area float offsets
#define OFF_WS0 0
#define OFF_WD0 128
#define OFF_CS0 256
#define OFF_CD0 258
#define OFF_U1  260
#define OFF_C1  324
#define OFF_WS1 512
#define OFF_WD1 768
#define OFF_CS1 1024
#define OFF_CD1 1026
#define FOLD_FLOATS 4096

__device__ __forceinline__ unsigned encm(float f) {
  unsigned u = __float_as_uint(f);
  return (u & 0x80000000u) ? ~u : (u | 0x80000000u);
}
__device__ __forceinline__ float decm(unsigned u) {
  return (u & 0x80000000u) ? __uint_as_float(u & 0x7FFFFFFFu) : __uint_as_float(~u);
}

// ---------------- fold: precompute a_s/a_d/a_e-contracted weight vectors ----------------
__global__ void fold_k(const float* __restrict__ Wn0, const float* __restrict__ bn0,
                       const float* __restrict__ as0, const float* __restrict__ ad0,
                       const float* __restrict__ We1, const float* __restrict__ be1,
                       const float* __restrict__ ae1,
                       const float* __restrict__ Wn1, const float* __restrict__ bn1,
                       const float* __restrict__ as1, const float* __restrict__ ad1,
                       float* __restrict__ fold) {
  int t = threadIdx.x;  // 256
  for (int i = t; i < 128; i += 256) {        // ws0/wd0: Wn0[2,64,32] . a[2,32]
    int h = i >> 6, d = i & 63;
    float s = 0.f, sd = 0.f;
    for (int k = 0; k < 32; ++k) {
      float w = Wn0[h*2048 + d*32 + k];
      s  += w * as0[h*32 + k];
      sd += w * ad0[h*32 + k];
    }
    fold[OFF_WS0 + i] = s; fold[OFF_WD0 + i] = sd;
  }
  for (int i = t; i < 64; i += 256) {         // u1: We1[2,32,16] . ae1[2,16]
    int h = i >> 5, d = i & 31;
    float s = 0.f;
    for (int k = 0; k < 16; ++k) s += We1[h*512 + d*16 + k] * ae1[h*16 + k];
    fold[OFF_U1 + i] = s;
  }
  if (t < 256) {                              // ws1/wd1: Wn1[2,128,32] . a[2,32]
    int i = t, h = i >> 7, d = i & 127;
    float s = 0.f, sd = 0.f;
    for (int k = 0; k < 32; ++k) {
      float w = Wn1[h*4096 + d*32 + k];
      s  += w * as1[h*32 + k];
      sd += w * ad1[h*32 + k];
    }
    fold[OFF_WS1 + i] = s; fold[OFF_WD1 + i] = sd;
  }
  if (t < 2) {
    float cs = 0.f, cd = 0.f;
    for (int k = 0; k < 32; ++k) { cs += bn0[t*32+k]*as0[t*32+k]; cd += bn0[t*32+k]*ad0[t*32+k]; }
    fold[OFF_CS0 + t] = cs; fold[OFF_CD0 + t] = cd;
    float c1 = 0.f;
    for (int k = 0; k < 16; ++k) c1 += ae1[t*16+k]*be1[t*16+k];
    fold[OFF_C1 + t] = c1;
    float cs1 = 0.f, cd1 = 0.f;
    for (int k = 0; k < 32; ++k) { cs1 += bn1[t*32+k]*as1[t*32+k]; cd1 += bn1[t*32+k]*ad1[t*32+k]; }
    fold[OFF_CS1 + t] = cs1; fold[OFF_CD1 + t] = cd1;
  }
}

// ---------------- CSR build ----------------
__global__ void count_k(const int* __restrict__ dst, int* __restrict__ cnt) {
  int e = blockIdx.x*256 + threadIdx.x;
  if (e < EE) atomicAdd(&cnt[dst[e]], 1);
}

__global__ __launch_bounds__(1024) void scan1_k(const int* __restrict__ cnt, int* __restrict__ partial) {
  int tid = threadIdx.x, lane = tid & 63, w = tid >> 6;
  int i = blockIdx.x*1024 + tid;
  int v = (i < NN) ? cnt[i] : 0;
  #pragma unroll
  for (int d = 32; d > 0; d >>= 1) v += __shfl_down(v, d);
  __shared__ int wsum[16];
  if (lane == 0) wsum[w] = v;
  __syncthreads();
  if (tid == 0) { int s = 0; for (int q = 0; q < 16; ++q) s += wsum[q]; partial[blockIdx.x] = s; }
}

__global__ void scan2_k(int* __restrict__ partial, int* __restrict__ off) {  // <<<1,1>>>
  int s = 0;
  for (int b = 0; b < NCH; ++b) { int t = partial[b]; partial[b] = s; s += t; }
  off[NN] = s;
}

__global__ __launch_bounds__(1024) void scan3_k(const int* __restrict__ cnt, const int* __restrict__ pbase,
                                                int* __restrict__ off, int* __restrict__ cursor) {
  int tid = threadIdx.x, lane = tid & 63, w = tid >> 6;
  int i = blockIdx.x*1024 + tid;
  int v = (i < NN) ? cnt[i] : 0;
  int x = v;
  #pragma unroll
  for (int d = 1; d < 64; d <<= 1) { int t = __shfl_up(x, d); if (lane >= d) x += t; }
  __shared__ int wsum[16], wbase[16];
  if (lane == 63) wsum[w] = x;
  __syncthreads();
  if (tid == 0) { int s = 0; for (int q = 0; q < 16; ++q) { wbase[q] = s; s += wsum[q]; } }
  __syncthreads();
  int excl = pbase[blockIdx.x] + wbase[w] + x - v;
  if (i < NN) { off[i] = excl; cursor[i] = excl; }
}

__global__ void scatter_k(const int* __restrict__ dst, int* __restrict__ cursor,
                          int* __restrict__ pos, int* __restrict__ dstp) {
  int e = blockIdx.x*256 + threadIdx.x;
  if (e < EE) {
    int dn = dst[e];
    int p = atomicAdd(&cursor[dn], 1);
    pos[e] = p; dstp[p] = dn;
  }
}

// ---------------- layer-0 node pass: v0 = xn@Wv0+bv0, zs0/zd0 scalars ----------------
__global__ __launch_bounds__(128) void node0_k(const float* __restrict__ nt, const float* __restrict__ nl,
                                               const float* __restrict__ Wv0, const float* __restrict__ bv0,
                                               const float* __restrict__ fold,
                                               float* __restrict__ v0, float* __restrict__ zs0, float* __restrict__ zd0) {
  int n = blockIdx.x, tid = threadIdx.x;
  __shared__ float xn[64];
  if (tid < 64) xn[tid] = (tid < 14) ? nt[n*14 + tid] : nl[n*50 + tid - 14];
  __syncthreads();
  int h = tid >> 6, k = tid & 63;
  float acc = bv0[tid];
  const float* wp = Wv0 + h*4096 + k;
  #pragma unroll 8
  for (int d = 0; d < 64; ++d) acc += xn[d] * wp[d*64];
  v0[(size_t)n*128 + tid] = acc;
  if (tid < 64) {
    float x = xn[tid];
    float p0 = x * fold[OFF_WS0 + tid];
    float p1 = x * fold[OFF_WS0 + 64 + tid];
    float p2 = x * fold[OFF_WD0 + tid];
    float p3 = x * fold[OFF_WD0 + 64 + tid];
    #pragma unroll
    for (int o = 32; o > 0; o >>= 1) {
      p0 += __shfl_down(p0, o); p1 += __shfl_down(p1, o);
      p2 += __shfl_down(p2, o); p3 += __shfl_down(p3, o);
    }
    if (tid == 0) {
      zs0[n*2]   = p0 + fold[OFF_CS0];
      zs0[n*2+1] = p1 + fold[OFF_CS0+1];
      zd0[n*2]   = p2 + fold[OFF_CD0];
      zd0[n*2+1] = p3 + fold[OFF_CD0+1];
    }
  }
}

// ---------------- layer-0 edge pass: logits into ebuf[pos[e]] + fused atomicMax + l1 edge term ----------------
__global__ __launch_bounds__(256) void edge0_k(const float* __restrict__ xe,
                                               const int* __restrict__ src, const int* __restrict__ dst,
                                               const float* __restrict__ We0, const float* __restrict__ be0,
                                               const float* __restrict__ ae0, const float* __restrict__ ab0,
                                               const float* __restrict__ fold,
                                               const float* __restrict__ zs0, const float* __restrict__ zd0,
                                               const int* __restrict__ pos,
                                               float4* __restrict__ ebuf, float* __restrict__ et1p,
                                               unsigned* __restrict__ menc0) {
  __shared__ float W[1024], AE[32], BE[32], U1[64];
  int tid = threadIdx.x;
  for (int i = tid; i < 1024; i += 256) W[i] = We0[i];
  if (tid < 32) { AE[tid] = ae0[tid]; BE[tid] = be0[tid]; }
  if (tid < 64) U1[tid] = fold[OFF_U1 + tid];
  __syncthreads();
  int e = blockIdx.x*256 + tid;
  if (e >= EE) return;
  float x[32];
  const float4* xp = reinterpret_cast<const float4*>(xe + (size_t)e*32);
  #pragma unroll
  for (int q = 0; q < 8; ++q) {
    float4 f = xp[q];
    x[q*4] = f.x; x[q*4+1] = f.y; x[q*4+2] = f.z; x[q*4+3] = f.w;
  }
  float s0 = 0.f, s1 = 0.f, etA = 0.f, etB = 0.f;
  #pragma unroll
  for (int o = 0; o < 32; ++o) {
    float acc = BE[o];
    const float* wc = &W[(o >> 4)*512 + (o & 15)];
    #pragma unroll
    for (int d = 0; d < 32; ++d) acc += x[d] * wc[d*16];
    if (o < 16) s0 += AE[o]*acc; else s1 += AE[o]*acc;
    float lz = acc >= 0.f ? acc : 0.01f*acc;   // inter-layer leaky on xe1
    etA += lz * U1[o];
    etB += lz * U1[32 + o];
  }
  int sn = src[e], dn = dst[e];
  float l0 = zs0[sn*2]   + s0 + zd0[dn*2]   + ab0[0];
  float l1 = zs0[sn*2+1] + s1 + zd0[dn*2+1] + ab0[1];
  l0 = l0 >= 0.f ? l0 : 0.2f*l0;
  l1 = l1 >= 0.f ? l1 : 0.2f*l1;
  int p = pos[e];
  ebuf[p] = make_float4(__int_as_float(sn), l0, l1, 0.f);
  *reinterpret_cast<float2*>(et1p + (size_t)p*2) =
      make_float2(etA + fold[OFF_C1], etB + fold[OFF_C1+1]);
  atomicMax(&menc0[(size_t)dn*2],   encm(l0));
  atomicMax(&menc0[(size_t)dn*2+1], encm(l1));
}

// ---------------- layer-0 aggregate (batched, no rescale) fused with layer-1 node pass ----------------
__global__ __launch_bounds__(256) void agg0_k(const int* __restrict__ off,
                                              const float4* __restrict__ ebuf,
                                              const unsigned* __restrict__ menc,
                                              const float* __restrict__ v0,
                                              const float* __restrict__ Wv1, const float* __restrict__ bv1,
                                              const float* __restrict__ fold,
                                              float* __restrict__ v1, float* __restrict__ zs1, float* __restrict__ zd1) {
  int tid = threadIdx.x, w = tid >> 6, lane = tid & 63;
  int n = blockIdx.x*4 + w;
  __shared__ float xsh[4][128];
  float xa = 0.f, xb = 0.f;
  if (n < NN) {
    int st = off[n], en = off[n+1];
    float m0 = decm(menc[n*2]), m1 = decm(menc[n*2+1]);
    float d0 = 0.f, d1 = 0.f, aa = 0.f, ab = 0.f;
    for (int i = st; i < en; i += 8) {
      int jj[8]; float4 eb[8];
      #pragma unroll
      for (int q = 0; q < 8; ++q) jj[q] = (i+q < en) ? i+q : st;
      #pragma unroll
      for (int q = 0; q < 8; ++q) eb[q] = ebuf[jj[q]];
      #pragma unroll
      for (int q = 0; q < 8; ++q) {
        int sn = __float_as_int(eb[q].x);
        float2 vv = *reinterpret_cast<const float2*>(v0 + (size_t)sn*128 + lane*2);
        bool okq = (i+q) < en;
        float e0 = okq ? __expf(eb[q].y - m0) : 0.f;
        float e1 = okq ? __expf(eb[q].z - m1) : 0.f;
        float es = (lane < 32) ? e0 : e1;
        d0 += e0; d1 += e1;
        aa = fmaf(es, vv.x, aa); ab = fmaf(es, vv.y, ab);
      }
    }
    float den = ((lane < 32) ? d0 : d1) + 1e-9f;
    float ha = aa/den, hb = ab/den;
    xa = ha >= 0.f ? ha : 0.01f*ha;   // inter-layer leaky
    xb = hb >= 0.f ? hb : 0.01f*hb;
    xsh[w][lane*2] = xa; xsh[w][lane*2+1] = xb;
  }
  __syncthreads();
  if (n < NN) {
    float accA = bv1[lane], accB = bv1[64 + lane];
    #pragma unroll 8
    for (int d = 0; d < 128; ++d) {
      float xd = xsh[w][d];
      accA = fmaf(xd, Wv1[d*64 + lane], accA);
      accB = fmaf(xd, Wv1[8192 + d*64 + lane], accB);
    }
    v1[(size_t)n*128 + lane] = accA;
    v1[(size_t)n*128 + 64 + lane] = accB;
    int l2 = lane*2;
    float p0 = xa*fold[OFF_WS1+l2]       + xb*fold[OFF_WS1+l2+1];
    float p1 = xa*fold[OFF_WS1+128+l2]   + xb*fold[OFF_WS1+128+l2+1];
    float p2 = xa*fold[OFF_WD1+l2]       + xb*fold[OFF_WD1+l2+1];
    float p3 = xa*fold[OFF_WD1+128+l2]   + xb*fold[OFF_WD1+128+l2+1];
    #pragma unroll
    for (int o = 32; o > 0; o >>= 1) {
      p0 += __shfl_down(p0, o); p1 += __shfl_down(p1, o);
      p2 += __shfl_down(p2, o); p3 += __shfl_down(p3, o);
    }
    if (lane == 0) {
      zs1[n*2]   = p0 + fold[OFF_CS1];
      zs1[n*2+1] = p1 + fold[OFF_CS1+1];
      zd1[n*2]   = p2 + fold[OFF_CD1];
      zd1[n*2+1] = p3 + fold[OFF_CD1+1];
    }
  }
}

// ---------------- layer-1 edge logits + fused segmented max (dstp is sorted) ----------------
__global__ __launch_bounds__(256) void edge1_k(float4* __restrict__ ebuf, const int* __restrict__ dstp,
                                               const float* __restrict__ zs1, const float* __restrict__ zd1,
                                               const float* __restrict__ et1p, const float* __restrict__ ab1,
                                               unsigned* __restrict__ menc1) {
  int i = blockIdx.x*256 + threadIdx.x;
  int lane = threadIdx.x & 63;
  bool ok = i < EE;
  float l0 = 0.f, l1 = 0.f; int dn = -1;
  if (ok) {
    float4 eb = ebuf[i];
    int sn = __float_as_int(eb.x);
    dn = dstp[i];
    float2 et = *reinterpret_cast<const float2*>(et1p + (size_t)i*2);
    l0 = zs1[sn*2]   + et.x + zd1[dn*2]   + ab1[0];
    l1 = zs1[sn*2+1] + et.y + zd1[dn*2+1] + ab1[1];
    l0 = l0 >= 0.f ? l0 : 0.2f*l0;
    l1 = l1 >= 0.f ? l1 : 0.2f*l1;
    eb.y = l0; eb.z = l1;
    ebuf[i] = eb;
  }
  unsigned e0 = ok ? encm(l0) : 0u;
  unsigned e1 = ok ? encm(l1) : 0u;
  #pragma unroll
  for (int o = 1; o < 64; o <<= 1) {   // max is idempotent: shfl self-return at wave edge is safe
    int pdn = __shfl_down(dn, o);
    unsigned q0 = __shfl_down(e0, o);
    unsigned q1 = __shfl_down(e1, o);
    if (pdn == dn) { e0 = max(e0, q0); e1 = max(e1, q1); }
  }
  int prev = __shfl_up(dn, 1);
  if (ok && (lane == 0 || prev != dn)) {
    atomicMax(&menc1[(size_t)dn*2],   e0);
    atomicMax(&menc1[(size_t)dn*2+1], e1);
  }
}

__global__ void outinit_k(const float* __restrict__ fcb, float* __restrict__ out) {
  int i = threadIdx.x;  // 128
  out[i] = fcb[i & 1];
}

// ---------------- layer-1 aggregate fused with final FC -> per-node partials ----------------
__global__ __launch_bounds__(256) void agg1_k(const int* __restrict__ off,
                                              const float4* __restrict__ ebuf,
                                              const unsigned* __restrict__ menc,
                                              const float* __restrict__ v1,
                                              const float* __restrict__ fcW,
                                              float* __restrict__ pnode) {
  int tid = threadIdx.x, w = tid >> 6, lane = tid & 63;
  int n = blockIdx.x*4 + w;
  if (n >= NN) return;
  int st = off[n], en = off[n+1];
  float m0 = decm(menc[n*2]), m1 = decm(menc[n*2+1]);
  float d0 = 0.f, d1 = 0.f, aa = 0.f, ab = 0.f;
  for (int i = st; i < en; i += 8) {
    int jj[8]; float4 eb[8];
    #pragma unroll
    for (int q = 0; q < 8; ++q) jj[q] = (i+q < en) ? i+q : st;
    #pragma unroll
    for (int q = 0; q < 8; ++q) eb[q] = ebuf[jj[q]];
    #pragma unroll
    for (int q = 0; q < 8; ++q) {
      int sn = __float_as_int(eb[q].x);
      float2 vv = *reinterpret_cast<const float2*>(v1 + (size_t)sn*128 + lane*2);
      bool okq = (i+q) < en;
      float e0 = okq ? __expf(eb[q].y - m0) : 0.f;
      float e1 = okq ? __expf(eb[q].z - m1) : 0.f;
      float es = (lane < 32) ? e0 : e1;
      d0 += e0; d1 += e1;
      aa = fmaf(es, vv.x, aa); ab = fmaf(es, vv.y, ab);
    }
  }
  float den = ((lane < 32) ? d0 : d1) + 1e-9f;
  float ha = aa/den, hb = ab/den;   // final layer: NO leaky
  int l2 = lane*2;
  float p0 = ha*fcW[l2*2]     + hb*fcW[(l2+1)*2];
  float p1 = ha*fcW[l2*2 + 1] + hb*fcW[(l2+1)*2 + 1];
  #pragma unroll
  for (int o = 32; o > 0; o >>= 1) {
    p0 += __shfl_down(p0, o);
    p1 += __shfl_down(p1, o);
  }
  if (lane == 0) {
    pnode[n*2]   = p0;
    pnode[n*2+1] = p1;
  }
}

// ---------------- graph readout: segmented sum over sorted gid, few atomics ----------------
__global__ __launch_bounds__(256) void gsum_k(const float* __restrict__ pnode, const int* __restrict__ gid,
                                              float* __restrict__ out) {
  int n = blockIdx.x*256 + threadIdx.x;
  int lane = threadIdx.x & 63;
  bool ok = n < NN;
  int g = ok ? gid[n] : -1;
  float p0 = ok ? pnode[n*2]   : 0.f;
  float p1 = ok ? pnode[n*2+1] : 0.f;
  #pragma unroll
  for (int o = 1; o < 64; o <<= 1) {
    int pg = __shfl_down(g, o);
    float q0 = __shfl_down(p0, o);
    float q1 = __shfl_down(p1, o);
    if ((lane + o) < 64 && pg == g) { p0 += q0; p1 += q1; }  // clamp: sum is NOT idempotent
  }
  int prev = __shfl_up(g, 1);
  if (ok && (lane == 0 || prev != g)) {
    atomicAdd(&out[g*2],     p0);
    atomicAdd(&out[g*2 + 1], p1);
  }
}

extern "C" void kernel_launch(void* const* d_in, const int* in_sizes, int n_in,
                              void* d_out, int out_size, void* d_ws, size_t ws_size,
                              hipStream_t stream) {
  const float* nt  = (const float*)d_in[0];
  const float* nl  = (const float*)d_in[1];
  const float* xe  = (const float*)d_in[2];
  const int*   src = (const int*)d_in[3];
  const int*   dst = (const int*)d_in[4];
  const int*   gid = (const int*)d_in[5];
  const float* Wn0 = (const float*)d_in[6],  *bn0 = (const float*)d_in[7];
  const float* Wv0 = (const float*)d_in[8],  *bv0 = (const float*)d_in[9];
  const float* We0 = (const float*)d_in[10], *be0 = (const float*)d_in[11];
  const float* as0 = (const float*)d_in[12], *ae0 = (const float*)d_in[13];
  const float* ad0 = (const float*)d_in[14], *ab0 = (const float*)d_in[15];
  const float* Wn1 = (const float*)d_in[16], *bn1 = (const float*)d_in[17];
  const float* Wv1 = (const float*)d_in[18], *bv1 = (const float*)d_in[19];
  const float* We1 = (const float*)d_in[20], *be1 = (const float*)d_in[21];
  const float* as1 = (const float*)d_in[22], *ae1 = (const float*)d_in[23];
  const float* ad1 = (const float*)d_in[24], *ab1 = (const float*)d_in[25];
  const float* fcW = (const float*)d_in[26], *fcb = (const float*)d_in[27];
  float* out = (float*)d_out;

  // workspace layout (floats, then uints, then ints); ~157 MB
  float* fold  = (float*)d_ws;                        // 4096
  float* zs    = fold + FOLD_FLOATS;                  // N*2 (layer0 then layer1)
  float* zd    = zs + (size_t)NN*2;                   // N*2
  float* v0    = zd + (size_t)NN*2;                   // N*128
  float* v1    = v0 + (size_t)NN*128;                 // N*128
  float* et1p  = v1 + (size_t)NN*128;                 // E*2
  float* ebuff = et1p + (size_t)EE*2;                 // E*4 (float4 per CSR pos)
  unsigned* menc0 = (unsigned*)(ebuff + (size_t)EE*4); // N*2
  unsigned* menc1 = menc0 + (size_t)NN*2;             // N*2
  float* pnode = (float*)(menc1 + (size_t)NN*2);      // N*2
  int* cnt    = (int*)(pnode + (size_t)NN*2);         // N
  int* off    = cnt + NN;                             // N+1
  int* cursor = off + NN + 1;                         // N
  int* pos    = cursor + NN;                          // E
  int* dstp   = pos + EE;                             // E
  int* part   = dstp + EE;                            // NCH
  float4* ebuf = (float4*)ebuff;

  hipMemsetAsync(cnt, 0, NN*sizeof(int), stream);
  hipMemsetAsync(menc0, 0, (size_t)NN*4*sizeof(unsigned), stream);  // menc0 + menc1
  fold_k<<<1, 256, 0, stream>>>(Wn0, bn0, as0, ad0, We1, be1, ae1, Wn1, bn1, as1, ad1, fold);
  count_k<<<EE/256, 256, 0, stream>>>(dst, cnt);
  scan1_k<<<NCH, 1024, 0, stream>>>(cnt, part);
  scan2_k<<<1, 1, 0, stream>>>(part, off);
  scan3_k<<<NCH, 1024, 0, stream>>>(cnt, part, off, cursor);
  scatter_k<<<EE/256, 256, 0, stream>>>(dst, cursor, pos, dstp);
  node0_k<<<NN, 128, 0, stream>>>(nt, nl, Wv0, bv0, fold, v0, zs, zd);
  edge0_k<<<EE/256, 256, 0, stream>>>(xe, src, dst, We0, be0, ae0, ab0, fold, zs, zd, pos, ebuf, et1p, menc0);
  agg0_k<<<NN/4, 256, 0, stream>>>(off, ebuf, menc0, v0, Wv1, bv1, fold, v1, zs, zd);
  edge1_k<<<EE/256, 256, 0, stream>>>(ebuf, dstp, zs, zd, et1p, ab1, menc1);
  outinit_k<<<1, 128, 0, stream>>>(fcb, out);
  agg1_k<<<NN/4, 256, 0, stream>>>(off, ebuf, menc1, v1, fcW, pnode);
  gsum_k<<<(NN + 255)/256, 256, 0, stream>>>(pnode, gid, out);
}

// Round 4
// 955.313 us; speedup vs baseline: 2.4142x; 1.1334x over previous
//
#include <hip/hip_runtime.h>

#define NN 100000
#define EE 1600000
#define NG 64
#define NCH 98  // ceil(NN/1024)

// fold-area float offsets
#define OFF_WS0 0
#define OFF_WD0 128
#define OFF_CS0 256
#define OFF_CD0 258
#define OFF_U1  260
#define OFF_C1  324
#define OFF_WS1 512
#define OFF_WD1 768
#define OFF_CS1 1024
#define OFF_CD1 1026
#define FOLD_FLOATS 4096

__device__ __forceinline__ unsigned encm(float f) {
  unsigned u = __float_as_uint(f);
  return (u & 0x80000000u) ? ~u : (u | 0x80000000u);
}
__device__ __forceinline__ float decm(unsigned u) {
  return (u & 0x80000000u) ? __uint_as_float(u & 0x7FFFFFFFu) : __uint_as_float(~u);
}

// ---------------- fold: precompute a_s/a_d/a_e-contracted weight vectors ----------------
__global__ void fold_k(const float* __restrict__ Wn0, const float* __restrict__ bn0,
                       const float* __restrict__ as0, const float* __restrict__ ad0,
                       const float* __restrict__ We1, const float* __restrict__ be1,
                       const float* __restrict__ ae1,
                       const float* __restrict__ Wn1, const float* __restrict__ bn1,
                       const float* __restrict__ as1, const float* __restrict__ ad1,
                       float* __restrict__ fold) {
  int t = threadIdx.x;  // 256
  for (int i = t; i < 128; i += 256) {        // ws0/wd0: Wn0[2,64,32] . a[2,32]
    int h = i >> 6, d = i & 63;
    float s = 0.f, sd = 0.f;
    for (int k = 0; k < 32; ++k) {
      float w = Wn0[h*2048 + d*32 + k];
      s  += w * as0[h*32 + k];
      sd += w * ad0[h*32 + k];
    }
    fold[OFF_WS0 + i] = s; fold[OFF_WD0 + i] = sd;
  }
  for (int i = t; i < 64; i += 256) {         // u1: We1[2,32,16] . ae1[2,16]
    int h = i >> 5, d = i & 31;
    float s = 0.f;
    for (int k = 0; k < 16; ++k) s += We1[h*512 + d*16 + k] * ae1[h*16 + k];
    fold[OFF_U1 + i] = s;
  }
  if (t < 256) {                              // ws1/wd1: Wn1[2,128,32] . a[2,32]
    int i = t, h = i >> 7, d = i & 127;
    float s = 0.f, sd = 0.f;
    for (int k = 0; k < 32; ++k) {
      float w = Wn1[h*4096 + d*32 + k];
      s  += w * as1[h*32 + k];
      sd += w * ad1[h*32 + k];
    }
    fold[OFF_WS1 + i] = s; fold[OFF_WD1 + i] = sd;
  }
  if (t < 2) {
    float cs = 0.f, cd = 0.f;
    for (int k = 0; k < 32; ++k) { cs += bn0[t*32+k]*as0[t*32+k]; cd += bn0[t*32+k]*ad0[t*32+k]; }
    fold[OFF_CS0 + t] = cs; fold[OFF_CD0 + t] = cd;
    float c1 = 0.f;
    for (int k = 0; k < 16; ++k) c1 += ae1[t*16+k]*be1[t*16+k];
    fold[OFF_C1 + t] = c1;
    float cs1 = 0.f, cd1 = 0.f;
    for (int k = 0; k < 32; ++k) { cs1 += bn1[t*32+k]*as1[t*32+k]; cd1 += bn1[t*32+k]*ad1[t*32+k]; }
    fold[OFF_CS1 + t] = cs1; fold[OFF_CD1 + t] = cd1;
  }
}

// ---------------- CSR build ----------------
__global__ void count_k(const int* __restrict__ dst, int* __restrict__ cnt) {
  int e = blockIdx.x*256 + threadIdx.x;
  if (e < EE) atomicAdd(&cnt[dst[e]], 1);
}

__global__ __launch_bounds__(1024) void scan1_k(const int* __restrict__ cnt, int* __restrict__ partial) {
  int tid = threadIdx.x, lane = tid & 63, w = tid >> 6;
  int i = blockIdx.x*1024 + tid;
  int v = (i < NN) ? cnt[i] : 0;
  #pragma unroll
  for (int d = 32; d > 0; d >>= 1) v += __shfl_down(v, d);
  __shared__ int wsum[16];
  if (lane == 0) wsum[w] = v;
  __syncthreads();
  if (tid == 0) { int s = 0; for (int q = 0; q < 16; ++q) s += wsum[q]; partial[blockIdx.x] = s; }
}

__global__ void scan2_k(int* __restrict__ partial, int* __restrict__ off) {  // <<<1,1>>>
  int s = 0;
  for (int b = 0; b < NCH; ++b) { int t = partial[b]; partial[b] = s; s += t; }
  off[NN] = s;
}

__global__ __launch_bounds__(1024) void scan3_k(const int* __restrict__ cnt, const int* __restrict__ pbase,
                                                int* __restrict__ off, int* __restrict__ cursor) {
  int tid = threadIdx.x, lane = tid & 63, w = tid >> 6;
  int i = blockIdx.x*1024 + tid;
  int v = (i < NN) ? cnt[i] : 0;
  int x = v;
  #pragma unroll
  for (int d = 1; d < 64; d <<= 1) { int t = __shfl_up(x, d); if (lane >= d) x += t; }
  __shared__ int wsum[16], wbase[16];
  if (lane == 63) wsum[w] = x;
  __syncthreads();
  if (tid == 0) { int s = 0; for (int q = 0; q < 16; ++q) { wbase[q] = s; s += wsum[q]; } }
  __syncthreads();
  int excl = pbase[blockIdx.x] + wbase[w] + x - v;
  if (i < NN) { off[i] = excl; cursor[i] = excl; }
}

__global__ void scatter_k(const int* __restrict__ dst, int* __restrict__ cursor,
                          int* __restrict__ pos, int* __restrict__ dstp) {
  int e = blockIdx.x*256 + threadIdx.x;
  if (e < EE) {
    int dn = dst[e];
    int p = atomicAdd(&cursor[dn], 1);
    pos[e] = p; dstp[p] = dn;
  }
}

// ---------------- layer-0 node pass: v0 = xn@Wv0+bv0, zs0/zd0 scalars ----------------
__global__ __launch_bounds__(128) void node0_k(const float* __restrict__ nt, const float* __restrict__ nl,
                                               const float* __restrict__ Wv0, const float* __restrict__ bv0,
                                               const float* __restrict__ fold,
                                               float* __restrict__ v0, float* __restrict__ zs0, float* __restrict__ zd0) {
  int n = blockIdx.x, tid = threadIdx.x;
  __shared__ float xn[64];
  if (tid < 64) xn[tid] = (tid < 14) ? nt[n*14 + tid] : nl[n*50 + tid - 14];
  __syncthreads();
  int h = tid >> 6, k = tid & 63;
  float acc = bv0[tid];
  const float* wp = Wv0 + h*4096 + k;
  #pragma unroll 8
  for (int d = 0; d < 64; ++d) acc += xn[d] * wp[d*64];
  v0[(size_t)n*128 + tid] = acc;
  if (tid < 64) {
    float x = xn[tid];
    float p0 = x * fold[OFF_WS0 + tid];
    float p1 = x * fold[OFF_WS0 + 64 + tid];
    float p2 = x * fold[OFF_WD0 + tid];
    float p3 = x * fold[OFF_WD0 + 64 + tid];
    #pragma unroll
    for (int o = 32; o > 0; o >>= 1) {
      p0 += __shfl_down(p0, o); p1 += __shfl_down(p1, o);
      p2 += __shfl_down(p2, o); p3 += __shfl_down(p3, o);
    }
    if (tid == 0) {
      zs0[n*2]   = p0 + fold[OFF_CS0];
      zs0[n*2+1] = p1 + fold[OFF_CS0+1];
      zd0[n*2]   = p2 + fold[OFF_CD0];
      zd0[n*2+1] = p3 + fold[OFF_CD0+1];
    }
  }
}

// ---------------- layer-0 edge pass: logits into ebuf[pos[e]] + fused atomicMax + l1 edge term ----------------
__global__ __launch_bounds__(256) void edge0_k(const float* __restrict__ xe,
                                               const int* __restrict__ src, const int* __restrict__ dst,
                                               const float* __restrict__ We0, const float* __restrict__ be0,
                                               const float* __restrict__ ae0, const float* __restrict__ ab0,
                                               const float* __restrict__ fold,
                                               const float* __restrict__ zs0, const float* __restrict__ zd0,
                                               const int* __restrict__ pos,
                                               float4* __restrict__ ebuf, float* __restrict__ et1p,
                                               unsigned* __restrict__ menc0) {
  __shared__ float W[1024], AE[32], BE[32], U1[64];
  int tid = threadIdx.x;
  for (int i = tid; i < 1024; i += 256) W[i] = We0[i];
  if (tid < 32) { AE[tid] = ae0[tid]; BE[tid] = be0[tid]; }
  if (tid < 64) U1[tid] = fold[OFF_U1 + tid];
  __syncthreads();
  int e = blockIdx.x*256 + tid;
  if (e >= EE) return;
  float x[32];
  const float4* xp = reinterpret_cast<const float4*>(xe + (size_t)e*32);
  #pragma unroll
  for (int q = 0; q < 8; ++q) {
    float4 f = xp[q];
    x[q*4] = f.x; x[q*4+1] = f.y; x[q*4+2] = f.z; x[q*4+3] = f.w;
  }
  float s0 = 0.f, s1 = 0.f, etA = 0.f, etB = 0.f;
  #pragma unroll
  for (int o = 0; o < 32; ++o) {
    float acc = BE[o];
    const float* wc = &W[(o >> 4)*512 + (o & 15)];
    #pragma unroll
    for (int d = 0; d < 32; ++d) acc += x[d] * wc[d*16];
    if (o < 16) s0 += AE[o]*acc; else s1 += AE[o]*acc;
    float lz = acc >= 0.f ? acc : 0.01f*acc;   // inter-layer leaky on xe1
    etA += lz * U1[o];
    etB += lz * U1[32 + o];
  }
  int sn = src[e], dn = dst[e];
  float l0 = zs0[sn*2]   + s0 + zd0[dn*2]   + ab0[0];
  float l1 = zs0[sn*2+1] + s1 + zd0[dn*2+1] + ab0[1];
  l0 = l0 >= 0.f ? l0 : 0.2f*l0;
  l1 = l1 >= 0.f ? l1 : 0.2f*l1;
  int p = pos[e];
  ebuf[p] = make_float4(__int_as_float(sn), l0, l1, 0.f);
  *reinterpret_cast<float2*>(et1p + (size_t)p*2) =
      make_float2(etA + fold[OFF_C1], etB + fold[OFF_C1+1]);
  atomicMax(&menc0[(size_t)dn*2],   encm(l0));
  atomicMax(&menc0[(size_t)dn*2+1], encm(l1));
}

// ---------------- layer-0 aggregate: dual-edge float4 gathers, 4 nodes/wave, fused l1 node MLP ----------------
__global__ __launch_bounds__(256) void agg0_k(const int* __restrict__ off,
                                              const float4* __restrict__ ebuf,
                                              const unsigned* __restrict__ menc,
                                              const float* __restrict__ v0,
                                              const float* __restrict__ Wv1, const float* __restrict__ bv1,
                                              const float* __restrict__ fold,
                                              float* __restrict__ v1, float* __restrict__ zs1, float* __restrict__ zd1) {
  int tid = threadIdx.x, w = tid >> 6, lane = tid & 63;
  int sl = lane & 31, half = lane >> 5;
  int base = blockIdx.x*16 + w*4;      // grid 6250 * 16 nodes = 100000 exactly
  __shared__ float xsh[16][128];
  // ---- gather + softmax-normalize, one node at a time; 2 edges concurrent (half-waves) ----
  #pragma unroll 1
  for (int k = 0; k < 4; ++k) {
    int n = base + k;
    int st = off[n], en = off[n+1];
    float m = (sl < 16) ? decm(menc[n*2]) : decm(menc[n*2+1]);
    float ax = 0.f, ay = 0.f, az = 0.f, aw = 0.f, den = 0.f;
    for (int i = st; i < en; i += 16) {
      float4 eb[8];
      #pragma unroll
      for (int q = 0; q < 8; ++q) { int j = i + q*2 + half; eb[q] = ebuf[(j < en) ? j : st]; }
      #pragma unroll
      for (int q = 0; q < 8; ++q) {
        int sn = __float_as_int(eb[q].x);
        float4 vv = *reinterpret_cast<const float4*>(v0 + (size_t)sn*128 + sl*4);
        bool okq = (i + q*2 + half) < en;
        float s = (sl < 16) ? eb[q].y : eb[q].z;
        float e = okq ? __expf(s - m) : 0.f;
        den += e;
        ax = fmaf(e, vv.x, ax); ay = fmaf(e, vv.y, ay);
        az = fmaf(e, vv.z, az); aw = fmaf(e, vv.w, aw);
      }
    }
    ax += __shfl_xor(ax, 32); ay += __shfl_xor(ay, 32);
    az += __shfl_xor(az, 32); aw += __shfl_xor(aw, 32);
    den += __shfl_xor(den, 32);
    float inv = 1.f / (den + 1e-9f);
    float x0 = ax*inv, x1 = ay*inv, x2 = az*inv, x3 = aw*inv;
    x0 = x0 >= 0.f ? x0 : 0.01f*x0;  // inter-layer leaky
    x1 = x1 >= 0.f ? x1 : 0.01f*x1;
    x2 = x2 >= 0.f ? x2 : 0.01f*x2;
    x3 = x3 >= 0.f ? x3 : 0.01f*x3;
    if (lane < 32) {
      float4 xq = make_float4(x0, x1, x2, x3);
      *reinterpret_cast<float4*>(&xsh[w*4 + k][sl*4]) = xq;
    }
  }
  // ---- layer-1 node MLP for the wave's 4 nodes (Wv1 read once per 4 nodes) ----
  float bA = bv1[lane], bB = bv1[64 + lane];
  float a0 = bA, a1 = bA, a2 = bA, a3 = bA;
  float b0 = bB, b1 = bB, b2 = bB, b3 = bB;
  const float* xr0 = xsh[w*4 + 0];
  const float* xr1 = xsh[w*4 + 1];
  const float* xr2 = xsh[w*4 + 2];
  const float* xr3 = xsh[w*4 + 3];
  #pragma unroll 4
  for (int d4 = 0; d4 < 32; ++d4) {
    float4 xv0 = *reinterpret_cast<const float4*>(xr0 + d4*4);
    float4 xv1 = *reinterpret_cast<const float4*>(xr1 + d4*4);
    float4 xv2 = *reinterpret_cast<const float4*>(xr2 + d4*4);
    float4 xv3 = *reinterpret_cast<const float4*>(xr3 + d4*4);
    #pragma unroll
    for (int c = 0; c < 4; ++c) {
      int d = d4*4 + c;
      float w0 = Wv1[d*64 + lane];
      float w1 = Wv1[8192 + d*64 + lane];
      float q0 = (c == 0) ? xv0.x : (c == 1) ? xv0.y : (c == 2) ? xv0.z : xv0.w;
      float q1 = (c == 0) ? xv1.x : (c == 1) ? xv1.y : (c == 2) ? xv1.z : xv1.w;
      float q2 = (c == 0) ? xv2.x : (c == 1) ? xv2.y : (c == 2) ? xv2.z : xv2.w;
      float q3 = (c == 0) ? xv3.x : (c == 1) ? xv3.y : (c == 2) ? xv3.z : xv3.w;
      a0 = fmaf(q0, w0, a0); b0 = fmaf(q0, w1, b0);
      a1 = fmaf(q1, w0, a1); b1 = fmaf(q1, w1, b1);
      a2 = fmaf(q2, w0, a2); b2 = fmaf(q2, w1, b2);
      a3 = fmaf(q3, w0, a3); b3 = fmaf(q3, w1, b3);
    }
  }
  {
    int n0 = base, n1 = base+1, n2 = base+2, n3 = base+3;
    v1[(size_t)n0*128 + lane] = a0; v1[(size_t)n0*128 + 64 + lane] = b0;
    v1[(size_t)n1*128 + lane] = a1; v1[(size_t)n1*128 + 64 + lane] = b1;
    v1[(size_t)n2*128 + lane] = a2; v1[(size_t)n2*128 + 64 + lane] = b2;
    v1[(size_t)n3*128 + lane] = a3; v1[(size_t)n3*128 + 64 + lane] = b3;
  }
  // ---- zs1/zd1 scalars per node ----
  #pragma unroll 1
  for (int k = 0; k < 4; ++k) {
    int n = base + k;
    float xl = xsh[w*4 + k][lane], xh = xsh[w*4 + k][64 + lane];
    float p0 = xl*fold[OFF_WS1 + lane]       + xh*fold[OFF_WS1 + 64 + lane];
    float p1 = xl*fold[OFF_WS1 + 128 + lane] + xh*fold[OFF_WS1 + 192 + lane];
    float p2 = xl*fold[OFF_WD1 + lane]       + xh*fold[OFF_WD1 + 64 + lane];
    float p3 = xl*fold[OFF_WD1 + 128 + lane] + xh*fold[OFF_WD1 + 192 + lane];
    #pragma unroll
    for (int o = 32; o > 0; o >>= 1) {
      p0 += __shfl_down(p0, o); p1 += __shfl_down(p1, o);
      p2 += __shfl_down(p2, o); p3 += __shfl_down(p3, o);
    }
    if (lane == 0) {
      zs1[n*2]   = p0 + fold[OFF_CS1];
      zs1[n*2+1] = p1 + fold[OFF_CS1+1];
      zd1[n*2]   = p2 + fold[OFF_CD1];
      zd1[n*2+1] = p3 + fold[OFF_CD1+1];
    }
  }
}

// ---------------- layer-1 edge logits + fused segmented max (dstp is sorted) ----------------
__global__ __launch_bounds__(256) void edge1_k(float4* __restrict__ ebuf, const int* __restrict__ dstp,
                                               const float* __restrict__ zs1, const float* __restrict__ zd1,
                                               const float* __restrict__ et1p, const float* __restrict__ ab1,
                                               unsigned* __restrict__ menc1) {
  int i = blockIdx.x*256 + threadIdx.x;
  int lane = threadIdx.x & 63;
  bool ok = i < EE;
  float l0 = 0.f, l1 = 0.f; int dn = -1;
  if (ok) {
    float4 eb = ebuf[i];
    int sn = __float_as_int(eb.x);
    dn = dstp[i];
    float2 et = *reinterpret_cast<const float2*>(et1p + (size_t)i*2);
    l0 = zs1[sn*2]   + et.x + zd1[dn*2]   + ab1[0];
    l1 = zs1[sn*2+1] + et.y + zd1[dn*2+1] + ab1[1];
    l0 = l0 >= 0.f ? l0 : 0.2f*l0;
    l1 = l1 >= 0.f ? l1 : 0.2f*l1;
    eb.y = l0; eb.z = l1;
    ebuf[i] = eb;
  }
  unsigned e0 = ok ? encm(l0) : 0u;
  unsigned e1 = ok ? encm(l1) : 0u;
  #pragma unroll
  for (int o = 1; o < 64; o <<= 1) {   // max is idempotent: shfl self-return at wave edge is safe
    int pdn = __shfl_down(dn, o);
    unsigned q0 = __shfl_down(e0, o);
    unsigned q1 = __shfl_down(e1, o);
    if (pdn == dn) { e0 = max(e0, q0); e1 = max(e1, q1); }
  }
  int prev = __shfl_up(dn, 1);
  if (ok && (lane == 0 || prev != dn)) {
    atomicMax(&menc1[(size_t)dn*2],   e0);
    atomicMax(&menc1[(size_t)dn*2+1], e1);
  }
}

__global__ void outinit_k(const float* __restrict__ fcb, float* __restrict__ out) {
  int i = threadIdx.x;  // 128
  out[i] = fcb[i & 1];
}

// ---------------- layer-1 aggregate: dual-edge float4 gathers, 4 nodes/wave, fused FC ----------------
__global__ __launch_bounds__(256) void agg1_k(const int* __restrict__ off,
                                              const float4* __restrict__ ebuf,
                                              const unsigned* __restrict__ menc,
                                              const float* __restrict__ v1,
                                              const float* __restrict__ fcW,
                                              float* __restrict__ pnode) {
  int tid = threadIdx.x, w = tid >> 6, lane = tid & 63;
  int sl = lane & 31, half = lane >> 5;
  int base = blockIdx.x*16 + w*4;
  const float4* fw4 = reinterpret_cast<const float4*>(fcW);
  float4 fA = fw4[sl*2], fB = fw4[sl*2 + 1];   // fcW[(sl*4+c)*2 + {0,1}] interleaved
  #pragma unroll 1
  for (int k = 0; k < 4; ++k) {
    int n = base + k;
    int st = off[n], en = off[n+1];
    float m = (sl < 16) ? decm(menc[n*2]) : decm(menc[n*2+1]);
    float ax = 0.f, ay = 0.f, az = 0.f, aw = 0.f, den = 0.f;
    for (int i = st; i < en; i += 16) {
      float4 eb[8];
      #pragma unroll
      for (int q = 0; q < 8; ++q) { int j = i + q*2 + half; eb[q] = ebuf[(j < en) ? j : st]; }
      #pragma unroll
      for (int q = 0; q < 8; ++q) {
        int sn = __float_as_int(eb[q].x);
        float4 vv = *reinterpret_cast<const float4*>(v1 + (size_t)sn*128 + sl*4);
        bool okq = (i + q*2 + half) < en;
        float s = (sl < 16) ? eb[q].y : eb[q].z;
        float e = okq ? __expf(s - m) : 0.f;
        den += e;
        ax = fmaf(e, vv.x, ax); ay = fmaf(e, vv.y, ay);
        az = fmaf(e, vv.z, az); aw = fmaf(e, vv.w, aw);
      }
    }
    ax += __shfl_xor(ax, 32); ay += __shfl_xor(ay, 32);
    az += __shfl_xor(az, 32); aw += __shfl_xor(aw, 32);
    den += __shfl_xor(den, 32);
    float inv = 1.f / (den + 1e-9f);          // final layer: NO leaky
    float h0 = ax*inv, h1 = ay*inv, h2 = az*inv, h3 = aw*inv;
    float p0 = h0*fA.x + h1*fA.z + h2*fB.x + h3*fB.z;
    float p1 = h0*fA.y + h1*fA.w + h2*fB.y + h3*fB.w;
    #pragma unroll
    for (int o = 16; o > 0; o >>= 1) {        // halves replicated -> 32-wide tree is exact
      p0 += __shfl_down(p0, o);
      p1 += __shfl_down(p1, o);
    }
    if (lane == 0) {
      pnode[n*2]   = p0;
      pnode[n*2+1] = p1;
    }
  }
}

// ---------------- graph readout: segmented sum over sorted gid, few atomics ----------------
__global__ __launch_bounds__(256) void gsum_k(const float* __restrict__ pnode, const int* __restrict__ gid,
                                              float* __restrict__ out) {
  int n = blockIdx.x*256 + threadIdx.x;
  int lane = threadIdx.x & 63;
  bool ok = n < NN;
  int g = ok ? gid[n] : -1;
  float p0 = ok ? pnode[n*2]   : 0.f;
  float p1 = ok ? pnode[n*2+1] : 0.f;
  #pragma unroll
  for (int o = 1; o < 64; o <<= 1) {
    int pg = __shfl_down(g, o);
    float q0 = __shfl_down(p0, o);
    float q1 = __shfl_down(p1, o);
    if ((lane + o) < 64 && pg == g) { p0 += q0; p1 += q1; }  // clamp: sum is NOT idempotent
  }
  int prev = __shfl_up(g, 1);
  if (ok && (lane == 0 || prev != g)) {
    atomicAdd(&out[g*2],     p0);
    atomicAdd(&out[g*2 + 1], p1);
  }
}

extern "C" void kernel_launch(void* const* d_in, const int* in_sizes, int n_in,
                              void* d_out, int out_size, void* d_ws, size_t ws_size,
                              hipStream_t stream) {
  const float* nt  = (const float*)d_in[0];
  const float* nl  = (const float*)d_in[1];
  const float* xe  = (const float*)d_in[2];
  const int*   src = (const int*)d_in[3];
  const int*   dst = (const int*)d_in[4];
  const int*   gid = (const int*)d_in[5];
  const float* Wn0 = (const float*)d_in[6],  *bn0 = (const float*)d_in[7];
  const float* Wv0 = (const float*)d_in[8],  *bv0 = (const float*)d_in[9];
  const float* We0 = (const float*)d_in[10], *be0 = (const float*)d_in[11];
  const float* as0 = (const float*)d_in[12], *ae0 = (const float*)d_in[13];
  const float* ad0 = (const float*)d_in[14], *ab0 = (const float*)d_in[15];
  const float* Wn1 = (const float*)d_in[16], *bn1 = (const float*)d_in[17];
  const float* Wv1 = (const float*)d_in[18], *bv1 = (const float*)d_in[19];
  const float* We1 = (const float*)d_in[20], *be1 = (const float*)d_in[21];
  const float* as1 = (const float*)d_in[22], *ae1 = (const float*)d_in[23];
  const float* ad1 = (const float*)d_in[24], *ab1 = (const float*)d_in[25];
  const float* fcW = (const float*)d_in[26], *fcb = (const float*)d_in[27];
  float* out = (float*)d_out;

  // workspace layout (floats, then uints, then ints); ~157 MB
  float* fold  = (float*)d_ws;                        // 4096
  float* zs    = fold + FOLD_FLOATS;                  // N*2 (layer0 then layer1)
  float* zd    = zs + (size_t)NN*2;                   // N*2
  float* v0    = zd + (size_t)NN*2;                   // N*128
  float* v1    = v0 + (size_t)NN*128;                 // N*128
  float* et1p  = v1 + (size_t)NN*128;                 // E*2
  float* ebuff = et1p + (size_t)EE*2;                 // E*4 (float4 per CSR pos)
  unsigned* menc0 = (unsigned*)(ebuff + (size_t)EE*4); // N*2
  unsigned* menc1 = menc0 + (size_t)NN*2;             // N*2
  float* pnode = (float*)(menc1 + (size_t)NN*2);      // N*2
  int* cnt    = (int*)(pnode + (size_t)NN*2);         // N
  int* off    = cnt + NN;                             // N+1
  int* cursor = off + NN + 1;                         // N
  int* pos    = cursor + NN;                          // E
  int* dstp   = pos + EE;                             // E
  int* part   = dstp + EE;                            // NCH
  float4* ebuf = (float4*)ebuff;

  hipMemsetAsync(cnt, 0, NN*sizeof(int), stream);
  hipMemsetAsync(menc0, 0, (size_t)NN*4*sizeof(unsigned), stream);  // menc0 + menc1
  fold_k<<<1, 256, 0, stream>>>(Wn0, bn0, as0, ad0, We1, be1, ae1, Wn1, bn1, as1, ad1, fold);
  count_k<<<EE/256, 256, 0, stream>>>(dst, cnt);
  scan1_k<<<NCH, 1024, 0, stream>>>(cnt, part);
  scan2_k<<<1, 1, 0, stream>>>(part, off);
  scan3_k<<<NCH, 1024, 0, stream>>>(cnt, part, off, cursor);
  scatter_k<<<EE/256, 256, 0, stream>>>(dst, cursor, pos, dstp);
  node0_k<<<NN, 128, 0, stream>>>(nt, nl, Wv0, bv0, fold, v0, zs, zd);
  edge0_k<<<EE/256, 256, 0, stream>>>(xe, src, dst, We0, be0, ae0, ab0, fold, zs, zd, pos, ebuf, et1p, menc0);
  agg0_k<<<NN/16, 256, 0, stream>>>(off, ebuf, menc0, v0, Wv1, bv1, fold, v1, zs, zd);
  edge1_k<<<EE/256, 256, 0, stream>>>(ebuf, dstp, zs, zd, et1p, ab1, menc1);
  outinit_k<<<1, 128, 0, stream>>>(fcb, out);
  agg1_k<<<NN/16, 256, 0, stream>>>(off, ebuf, menc1, v1, fcW, pnode);
  gsum_k<<<(NN + 255)/256, 256, 0, stream>>>(pnode, gid, out);
}

// Round 5
// 753.697 us; speedup vs baseline: 3.0600x; 1.2675x over previous
//
#include <hip/hip_runtime.h>

#define NN 100000
#define EE 1600000
#define NG 64
#define NCH 98  // ceil(NN/1024)

// fold-area float offsets
#define OFF_WS0 0
#define OFF_WD0 128
#define OFF_CS0 256
#define OFF_CD0 258
#define OFF_U1  260
#define OFF_C1  324
#define OFF_WS1 512
#define OFF_WD1 768
#define OFF_CS1 1024
#define OFF_CD1 1026
#define OFF_WT0 2048   // transposed We0: [32 out][32 in]
#define FOLD_FLOATS 4096

__device__ __forceinline__ unsigned encm(float f) {
  unsigned u = __float_as_uint(f);
  return (u & 0x80000000u) ? ~u : (u | 0x80000000u);
}
__device__ __forceinline__ float decm(unsigned u) {
  return (u & 0x80000000u) ? __uint_as_float(u & 0x7FFFFFFFu) : __uint_as_float(~u);
}

// ---------------- fold: precompute contracted weight vectors + We0 transpose ----------------
__global__ void fold_k(const float* __restrict__ Wn0, const float* __restrict__ bn0,
                       const float* __restrict__ as0, const float* __restrict__ ad0,
                       const float* __restrict__ We0,
                       const float* __restrict__ We1, const float* __restrict__ be1,
                       const float* __restrict__ ae1,
                       const float* __restrict__ Wn1, const float* __restrict__ bn1,
                       const float* __restrict__ as1, const float* __restrict__ ad1,
                       float* __restrict__ fold) {
  int t = threadIdx.x;  // 256
  for (int i = t; i < 128; i += 256) {        // ws0/wd0: Wn0[2,64,32] . a[2,32]
    int h = i >> 6, d = i & 63;
    float s = 0.f, sd = 0.f;
    for (int k = 0; k < 32; ++k) {
      float w = Wn0[h*2048 + d*32 + k];
      s  += w * as0[h*32 + k];
      sd += w * ad0[h*32 + k];
    }
    fold[OFF_WS0 + i] = s; fold[OFF_WD0 + i] = sd;
  }
  for (int i = t; i < 64; i += 256) {         // u1: We1[2,32,16] . ae1[2,16]
    int h = i >> 5, d = i & 31;
    float s = 0.f;
    for (int k = 0; k < 16; ++k) s += We1[h*512 + d*16 + k] * ae1[h*16 + k];
    fold[OFF_U1 + i] = s;
  }
  for (int i = t; i < 1024; i += 256) {       // WT0[o][d] = We0[o>>4][d][o&15]
    int o = i >> 5, d = i & 31;
    fold[OFF_WT0 + o*32 + d] = We0[(o >> 4)*512 + d*16 + (o & 15)];
  }
  if (t < 256) {                              // ws1/wd1: Wn1[2,128,32] . a[2,32]
    int i = t, h = i >> 7, d = i & 127;
    float s = 0.f, sd = 0.f;
    for (int k = 0; k < 32; ++k) {
      float w = Wn1[h*4096 + d*32 + k];
      s  += w * as1[h*32 + k];
      sd += w * ad1[h*32 + k];
    }
    fold[OFF_WS1 + i] = s; fold[OFF_WD1 + i] = sd;
  }
  if (t < 2) {
    float cs = 0.f, cd = 0.f;
    for (int k = 0; k < 32; ++k) { cs += bn0[t*32+k]*as0[t*32+k]; cd += bn0[t*32+k]*ad0[t*32+k]; }
    fold[OFF_CS0 + t] = cs; fold[OFF_CD0 + t] = cd;
    float c1 = 0.f;
    for (int k = 0; k < 16; ++k) c1 += ae1[t*16+k]*be1[t*16+k];
    fold[OFF_C1 + t] = c1;
    float cs1 = 0.f, cd1 = 0.f;
    for (int k = 0; k < 32; ++k) { cs1 += bn1[t*32+k]*as1[t*32+k]; cd1 += bn1[t*32+k]*ad1[t*32+k]; }
    fold[OFF_CS1 + t] = cs1; fold[OFF_CD1 + t] = cd1;
  }
}

// ---------------- CSR build ----------------
__global__ void count_k(const int* __restrict__ dst, int* __restrict__ cnt) {
  int e = blockIdx.x*256 + threadIdx.x;
  if (e < EE) atomicAdd(&cnt[dst[e]], 1);
}

__global__ __launch_bounds__(1024) void scan1_k(const int* __restrict__ cnt, int* __restrict__ partial) {
  int tid = threadIdx.x, lane = tid & 63, w = tid >> 6;
  int i = blockIdx.x*1024 + tid;
  int v = (i < NN) ? cnt[i] : 0;
  #pragma unroll
  for (int d = 32; d > 0; d >>= 1) v += __shfl_down(v, d);
  __shared__ int wsum[16];
  if (lane == 0) wsum[w] = v;
  __syncthreads();
  if (tid == 0) { int s = 0; for (int q = 0; q < 16; ++q) s += wsum[q]; partial[blockIdx.x] = s; }
}

__global__ void scan2_k(int* __restrict__ partial, int* __restrict__ off) {  // <<<1,1>>>
  int s = 0;
  for (int b = 0; b < NCH; ++b) { int t = partial[b]; partial[b] = s; s += t; }
  off[NN] = s;
}

__global__ __launch_bounds__(1024) void scan3_k(const int* __restrict__ cnt, const int* __restrict__ pbase,
                                                int* __restrict__ off, int* __restrict__ cursor) {
  int tid = threadIdx.x, lane = tid & 63, w = tid >> 6;
  int i = blockIdx.x*1024 + tid;
  int v = (i < NN) ? cnt[i] : 0;
  int x = v;
  #pragma unroll
  for (int d = 1; d < 64; d <<= 1) { int t = __shfl_up(x, d); if (lane >= d) x += t; }
  __shared__ int wsum[16], wbase[16];
  if (lane == 63) wsum[w] = x;
  __syncthreads();
  if (tid == 0) { int s = 0; for (int q = 0; q < 16; ++q) { wbase[q] = s; s += wsum[q]; } }
  __syncthreads();
  int excl = pbase[blockIdx.x] + wbase[w] + x - v;
  if (i < NN) { off[i] = excl; cursor[i] = excl; }
}

__global__ void scatter_k(const int* __restrict__ dst, int* __restrict__ cursor, int* __restrict__ eid) {
  int e = blockIdx.x*256 + threadIdx.x;
  if (e < EE) { int p = atomicAdd(&cursor[dst[e]], 1); eid[p] = e; }
}

// ---------------- layer-0 v-projection: W in VGPRs, 8 nodes/block, xn via uniform s_loads ----------------
__global__ __launch_bounds__(128) void node0v_k(const float* __restrict__ nt, const float* __restrict__ nl,
                                                const float* __restrict__ Wv0, const float* __restrict__ bv0,
                                                float* __restrict__ v0) {
  int tid = threadIdx.x;
  int h = tid >> 6, k = tid & 63;
  float w[64];
  #pragma unroll
  for (int d = 0; d < 64; ++d) w[d] = Wv0[h*4096 + d*64 + k];
  float b = bv0[tid];
  int nb = blockIdx.x * 8;   // grid 12500 * 8 = 100000 exactly
  #pragma unroll 1
  for (int r = 0; r < 8; ++r) {
    int n = nb + r;
    const float* nrow = nt + (size_t)n*14;   // uniform addresses -> SGPR loads
    const float* lrow = nl + (size_t)n*50;
    float acc = b;
    #pragma unroll
    for (int d = 0; d < 14; ++d) acc = fmaf(nrow[d], w[d], acc);
    #pragma unroll
    for (int d = 0; d < 50; ++d) acc = fmaf(lrow[d], w[14 + d], acc);
    v0[(size_t)n*128 + tid] = acc;
  }
}

// ---------------- layer-0 z-scalars: one thread per node ----------------
__global__ __launch_bounds__(256) void nodez_k(const float* __restrict__ nt, const float* __restrict__ nl,
                                               const float* __restrict__ fold,
                                               float* __restrict__ zs0, float* __restrict__ zd0) {
  int n = blockIdx.x*256 + threadIdx.x;
  if (n >= NN) return;
  float p0 = 0.f, p1 = 0.f, p2 = 0.f, p3 = 0.f;
  #pragma unroll
  for (int d = 0; d < 64; ++d) {
    float x = (d < 14) ? nt[(size_t)n*14 + d] : nl[(size_t)n*50 + d - 14];
    p0 = fmaf(x, fold[OFF_WS0 + d],      p0);
    p1 = fmaf(x, fold[OFF_WS0 + 64 + d], p1);
    p2 = fmaf(x, fold[OFF_WD0 + d],      p2);
    p3 = fmaf(x, fold[OFF_WD0 + 64 + d], p3);
  }
  zs0[n*2]   = p0 + fold[OFF_CS0];
  zs0[n*2+1] = p1 + fold[OFF_CS0+1];
  zd0[n*2]   = p2 + fold[OFF_CD0];
  zd0[n*2+1] = p3 + fold[OFF_CD0+1];
}

// ---------------- layer-0 edge pass (CSR order): uniform-W MLP, coalesced writes, segmented max ----------------
__global__ __launch_bounds__(256) void edge0_k(const float* __restrict__ xe,
                                               const int* __restrict__ src, const int* __restrict__ dst,
                                               const int* __restrict__ eid,
                                               const float* __restrict__ be0,
                                               const float* __restrict__ ae0, const float* __restrict__ ab0,
                                               const float* __restrict__ fold,
                                               const float* __restrict__ zs0, const float* __restrict__ zd0,
                                               float4* __restrict__ ebuf, float* __restrict__ et1p,
                                               unsigned* __restrict__ menc0) {
  int p = blockIdx.x*256 + threadIdx.x;   // grid exact: EE/256
  int lane = threadIdx.x & 63;
  int e = eid[p];
  int sn = src[e], dn = dst[e];
  const float4* xp = reinterpret_cast<const float4*>(xe + (size_t)e*32);
  float4 xv[8];
  #pragma unroll
  for (int q = 0; q < 8; ++q) xv[q] = xp[q];
  const float* WT = fold + OFF_WT0;
  const float* U1 = fold + OFF_U1;
  float s0 = 0.f, s1 = 0.f, etA = 0.f, etB = 0.f;
  #pragma unroll 4
  for (int o = 0; o < 16; ++o) {          // head 0
    float acc = be0[o];
    #pragma unroll
    for (int q = 0; q < 8; ++q) {         // WT row: wave-uniform -> SGPR loads
      float4 w = *reinterpret_cast<const float4*>(WT + o*32 + q*4);
      acc = fmaf(xv[q].x, w.x, acc); acc = fmaf(xv[q].y, w.y, acc);
      acc = fmaf(xv[q].z, w.z, acc); acc = fmaf(xv[q].w, w.w, acc);
    }
    s0 = fmaf(ae0[o], acc, s0);
    float lz = acc >= 0.f ? acc : 0.01f*acc;
    etA = fmaf(lz, U1[o], etA); etB = fmaf(lz, U1[32 + o], etB);
  }
  #pragma unroll 4
  for (int o = 16; o < 32; ++o) {         // head 1
    float acc = be0[o];
    #pragma unroll
    for (int q = 0; q < 8; ++q) {
      float4 w = *reinterpret_cast<const float4*>(WT + o*32 + q*4);
      acc = fmaf(xv[q].x, w.x, acc); acc = fmaf(xv[q].y, w.y, acc);
      acc = fmaf(xv[q].z, w.z, acc); acc = fmaf(xv[q].w, w.w, acc);
    }
    s1 = fmaf(ae0[o], acc, s1);
    float lz = acc >= 0.f ? acc : 0.01f*acc;
    etA = fmaf(lz, U1[o], etA); etB = fmaf(lz, U1[32 + o], etB);
  }
  float2 zsv = *reinterpret_cast<const float2*>(zs0 + (size_t)sn*2);
  float2 zdv = *reinterpret_cast<const float2*>(zd0 + (size_t)dn*2);
  float l0 = zsv.x + s0 + zdv.x + ab0[0];
  float l1 = zsv.y + s1 + zdv.y + ab0[1];
  l0 = l0 >= 0.f ? l0 : 0.2f*l0;
  l1 = l1 >= 0.f ? l1 : 0.2f*l1;
  ebuf[p] = make_float4(__int_as_float(sn), l0, l1, __int_as_float(dn));
  *reinterpret_cast<float2*>(et1p + (size_t)p*2) =
      make_float2(etA + fold[OFF_C1], etB + fold[OFF_C1+1]);
  // segmented max over sorted dn
  unsigned e0 = encm(l0), e1 = encm(l1);
  #pragma unroll
  for (int o = 1; o < 64; o <<= 1) {      // max idempotent: wave-edge self-return safe
    int pdn = __shfl_down(dn, o);
    unsigned q0 = __shfl_down(e0, o);
    unsigned q1 = __shfl_down(e1, o);
    if (pdn == dn) { e0 = max(e0, q0); e1 = max(e1, q1); }
  }
  int prev = __shfl_up(dn, 1);
  if (lane == 0 || prev != dn) {
    atomicMax(&menc0[(size_t)dn*2],   e0);
    atomicMax(&menc0[(size_t)dn*2+1], e1);
  }
}

// ---------------- layer-0 aggregate: dual-edge float4 gathers, 4 nodes/wave, fused l1 node MLP ----------------
__global__ __launch_bounds__(256) void agg0_k(const int* __restrict__ off,
                                              const float4* __restrict__ ebuf,
                                              const unsigned* __restrict__ menc,
                                              const float* __restrict__ v0,
                                              const float* __restrict__ Wv1, const float* __restrict__ bv1,
                                              const float* __restrict__ fold,
                                              float* __restrict__ v1, float* __restrict__ zs1, float* __restrict__ zd1) {
  int tid = threadIdx.x, w = tid >> 6, lane = tid & 63;
  int sl = lane & 31, half = lane >> 5;
  int base = blockIdx.x*16 + w*4;      // grid 6250 * 16 nodes = 100000 exactly
  __shared__ float xsh[16][128];
  // ---- gather + softmax-normalize, one node at a time; 2 edges concurrent (half-waves) ----
  #pragma unroll 1
  for (int k = 0; k < 4; ++k) {
    int n = base + k;
    int st = off[n], en = off[n+1];
    float m = (sl < 16) ? decm(menc[n*2]) : decm(menc[n*2+1]);
    float ax = 0.f, ay = 0.f, az = 0.f, aw = 0.f, den = 0.f;
    for (int i = st; i < en; i += 16) {
      float4 eb[8];
      #pragma unroll
      for (int q = 0; q < 8; ++q) { int j = i + q*2 + half; eb[q] = ebuf[(j < en) ? j : st]; }
      #pragma unroll
      for (int q = 0; q < 8; ++q) {
        int sn = __float_as_int(eb[q].x);
        float4 vv = *reinterpret_cast<const float4*>(v0 + (size_t)sn*128 + sl*4);
        bool okq = (i + q*2 + half) < en;
        float s = (sl < 16) ? eb[q].y : eb[q].z;
        float e = okq ? __expf(s - m) : 0.f;
        den += e;
        ax = fmaf(e, vv.x, ax); ay = fmaf(e, vv.y, ay);
        az = fmaf(e, vv.z, az); aw = fmaf(e, vv.w, aw);
      }
    }
    ax += __shfl_xor(ax, 32); ay += __shfl_xor(ay, 32);
    az += __shfl_xor(az, 32); aw += __shfl_xor(aw, 32);
    den += __shfl_xor(den, 32);
    float inv = 1.f / (den + 1e-9f);
    float x0 = ax*inv, x1 = ay*inv, x2 = az*inv, x3 = aw*inv;
    x0 = x0 >= 0.f ? x0 : 0.01f*x0;  // inter-layer leaky
    x1 = x1 >= 0.f ? x1 : 0.01f*x1;
    x2 = x2 >= 0.f ? x2 : 0.01f*x2;
    x3 = x3 >= 0.f ? x3 : 0.01f*x3;
    if (lane < 32) {
      float4 xq = make_float4(x0, x1, x2, x3);
      *reinterpret_cast<float4*>(&xsh[w*4 + k][sl*4]) = xq;
    }
  }
  __syncthreads();
  // ---- layer-1 node MLP for the wave's 4 nodes (Wv1 read once per 4 nodes) ----
  float bA = bv1[lane], bB = bv1[64 + lane];
  float a0 = bA, a1 = bA, a2 = bA, a3 = bA;
  float b0 = bB, b1 = bB, b2 = bB, b3 = bB;
  const float* xr0 = xsh[w*4 + 0];
  const float* xr1 = xsh[w*4 + 1];
  const float* xr2 = xsh[w*4 + 2];
  const float* xr3 = xsh[w*4 + 3];
  #pragma unroll 4
  for (int d4 = 0; d4 < 32; ++d4) {
    float4 xv0 = *reinterpret_cast<const float4*>(xr0 + d4*4);
    float4 xv1 = *reinterpret_cast<const float4*>(xr1 + d4*4);
    float4 xv2 = *reinterpret_cast<const float4*>(xr2 + d4*4);
    float4 xv3 = *reinterpret_cast<const float4*>(xr3 + d4*4);
    #pragma unroll
    for (int c = 0; c < 4; ++c) {
      int d = d4*4 + c;
      float w0 = Wv1[d*64 + lane];
      float w1 = Wv1[8192 + d*64 + lane];
      float q0 = (c == 0) ? xv0.x : (c == 1) ? xv0.y : (c == 2) ? xv0.z : xv0.w;
      float q1 = (c == 0) ? xv1.x : (c == 1) ? xv1.y : (c == 2) ? xv1.z : xv1.w;
      float q2 = (c == 0) ? xv2.x : (c == 1) ? xv2.y : (c == 2) ? xv2.z : xv2.w;
      float q3 = (c == 0) ? xv3.x : (c == 1) ? xv3.y : (c == 2) ? xv3.z : xv3.w;
      a0 = fmaf(q0, w0, a0); b0 = fmaf(q0, w1, b0);
      a1 = fmaf(q1, w0, a1); b1 = fmaf(q1, w1, b1);
      a2 = fmaf(q2, w0, a2); b2 = fmaf(q2, w1, b2);
      a3 = fmaf(q3, w0, a3); b3 = fmaf(q3, w1, b3);
    }
  }
  {
    int n0 = base, n1 = base+1, n2 = base+2, n3 = base+3;
    v1[(size_t)n0*128 + lane] = a0; v1[(size_t)n0*128 + 64 + lane] = b0;
    v1[(size_t)n1*128 + lane] = a1; v1[(size_t)n1*128 + 64 + lane] = b1;
    v1[(size_t)n2*128 + lane] = a2; v1[(size_t)n2*128 + 64 + lane] = b2;
    v1[(size_t)n3*128 + lane] = a3; v1[(size_t)n3*128 + 64 + lane] = b3;
  }
  // ---- zs1/zd1 scalars per node ----
  #pragma unroll 1
  for (int k = 0; k < 4; ++k) {
    int n = base + k;
    float xl = xsh[w*4 + k][lane], xh = xsh[w*4 + k][64 + lane];
    float p0 = xl*fold[OFF_WS1 + lane]       + xh*fold[OFF_WS1 + 64 + lane];
    float p1 = xl*fold[OFF_WS1 + 128 + lane] + xh*fold[OFF_WS1 + 192 + lane];
    float p2 = xl*fold[OFF_WD1 + lane]       + xh*fold[OFF_WD1 + 64 + lane];
    float p3 = xl*fold[OFF_WD1 + 128 + lane] + xh*fold[OFF_WD1 + 192 + lane];
    #pragma unroll
    for (int o = 32; o > 0; o >>= 1) {
      p0 += __shfl_down(p0, o); p1 += __shfl_down(p1, o);
      p2 += __shfl_down(p2, o); p3 += __shfl_down(p3, o);
    }
    if (lane == 0) {
      zs1[n*2]   = p0 + fold[OFF_CS1];
      zs1[n*2+1] = p1 + fold[OFF_CS1+1];
      zd1[n*2]   = p2 + fold[OFF_CD1];
      zd1[n*2+1] = p3 + fold[OFF_CD1+1];
    }
  }
}

// ---------------- layer-1 edge logits + fused segmented max (dn from ebuf.w, sorted) ----------------
__global__ __launch_bounds__(256) void edge1_k(float4* __restrict__ ebuf,
                                               const float* __restrict__ zs1, const float* __restrict__ zd1,
                                               const float* __restrict__ et1p, const float* __restrict__ ab1,
                                               unsigned* __restrict__ menc1) {
  int i = blockIdx.x*256 + threadIdx.x;
  int lane = threadIdx.x & 63;
  bool ok = i < EE;
  float l0 = 0.f, l1 = 0.f; int dn = -1;
  if (ok) {
    float4 eb = ebuf[i];
    int sn = __float_as_int(eb.x);
    dn = __float_as_int(eb.w);
    float2 et = *reinterpret_cast<const float2*>(et1p + (size_t)i*2);
    l0 = zs1[sn*2]   + et.x + zd1[dn*2]   + ab1[0];
    l1 = zs1[sn*2+1] + et.y + zd1[dn*2+1] + ab1[1];
    l0 = l0 >= 0.f ? l0 : 0.2f*l0;
    l1 = l1 >= 0.f ? l1 : 0.2f*l1;
    eb.y = l0; eb.z = l1;
    ebuf[i] = eb;
  }
  unsigned e0 = ok ? encm(l0) : 0u;
  unsigned e1 = ok ? encm(l1) : 0u;
  #pragma unroll
  for (int o = 1; o < 64; o <<= 1) {   // max is idempotent: shfl self-return at wave edge is safe
    int pdn = __shfl_down(dn, o);
    unsigned q0 = __shfl_down(e0, o);
    unsigned q1 = __shfl_down(e1, o);
    if (pdn == dn) { e0 = max(e0, q0); e1 = max(e1, q1); }
  }
  int prev = __shfl_up(dn, 1);
  if (ok && (lane == 0 || prev != dn)) {
    atomicMax(&menc1[(size_t)dn*2],   e0);
    atomicMax(&menc1[(size_t)dn*2+1], e1);
  }
}

__global__ void outinit_k(const float* __restrict__ fcb, float* __restrict__ out) {
  int i = threadIdx.x;  // 128
  out[i] = fcb[i & 1];
}

// ---------------- layer-1 aggregate: dual-edge float4 gathers, 4 nodes/wave, fused FC ----------------
__global__ __launch_bounds__(256) void agg1_k(const int* __restrict__ off,
                                              const float4* __restrict__ ebuf,
                                              const unsigned* __restrict__ menc,
                                              const float* __restrict__ v1,
                                              const float* __restrict__ fcW,
                                              float* __restrict__ pnode) {
  int tid = threadIdx.x, w = tid >> 6, lane = tid & 63;
  int sl = lane & 31, half = lane >> 5;
  int base = blockIdx.x*16 + w*4;
  const float4* fw4 = reinterpret_cast<const float4*>(fcW);
  float4 fA = fw4[sl*2], fB = fw4[sl*2 + 1];   // fcW[(sl*4+c)*2 + {0,1}] interleaved
  #pragma unroll 1
  for (int k = 0; k < 4; ++k) {
    int n = base + k;
    int st = off[n], en = off[n+1];
    float m = (sl < 16) ? decm(menc[n*2]) : decm(menc[n*2+1]);
    float ax = 0.f, ay = 0.f, az = 0.f, aw = 0.f, den = 0.f;
    for (int i = st; i < en; i += 16) {
      float4 eb[8];
      #pragma unroll
      for (int q = 0; q < 8; ++q) { int j = i + q*2 + half; eb[q] = ebuf[(j < en) ? j : st]; }
      #pragma unroll
      for (int q = 0; q < 8; ++q) {
        int sn = __float_as_int(eb[q].x);
        float4 vv = *reinterpret_cast<const float4*>(v1 + (size_t)sn*128 + sl*4);
        bool okq = (i + q*2 + half) < en;
        float s = (sl < 16) ? eb[q].y : eb[q].z;
        float e = okq ? __expf(s - m) : 0.f;
        den += e;
        ax = fmaf(e, vv.x, ax); ay = fmaf(e, vv.y, ay);
        az = fmaf(e, vv.z, az); aw = fmaf(e, vv.w, aw);
      }
    }
    ax += __shfl_xor(ax, 32); ay += __shfl_xor(ay, 32);
    az += __shfl_xor(az, 32); aw += __shfl_xor(aw, 32);
    den += __shfl_xor(den, 32);
    float inv = 1.f / (den + 1e-9f);          // final layer: NO leaky
    float h0 = ax*inv, h1 = ay*inv, h2 = az*inv, h3 = aw*inv;
    float p0 = h0*fA.x + h1*fA.z + h2*fB.x + h3*fB.z;
    float p1 = h0*fA.y + h1*fA.w + h2*fB.y + h3*fB.w;
    #pragma unroll
    for (int o = 16; o > 0; o >>= 1) {        // halves replicated -> 32-wide tree is exact
      p0 += __shfl_down(p0, o);
      p1 += __shfl_down(p1, o);
    }
    if (lane == 0) {
      pnode[n*2]   = p0;
      pnode[n*2+1] = p1;
    }
  }
}

// ---------------- graph readout: segmented sum over sorted gid, few atomics ----------------
__global__ __launch_bounds__(256) void gsum_k(const float* __restrict__ pnode, const int* __restrict__ gid,
                                              float* __restrict__ out) {
  int n = blockIdx.x*256 + threadIdx.x;
  int lane = threadIdx.x & 63;
  bool ok = n < NN;
  int g = ok ? gid[n] : -1;
  float p0 = ok ? pnode[n*2]   : 0.f;
  float p1 = ok ? pnode[n*2+1] : 0.f;
  #pragma unroll
  for (int o = 1; o < 64; o <<= 1) {
    int pg = __shfl_down(g, o);
    float q0 = __shfl_down(p0, o);
    float q1 = __shfl_down(p1, o);
    if ((lane + o) < 64 && pg == g) { p0 += q0; p1 += q1; }  // clamp: sum is NOT idempotent
  }
  int prev = __shfl_up(g, 1);
  if (ok && (lane == 0 || prev != g)) {
    atomicAdd(&out[g*2],     p0);
    atomicAdd(&out[g*2 + 1], p1);
  }
}

extern "C" void kernel_launch(void* const* d_in, const int* in_sizes, int n_in,
                              void* d_out, int out_size, void* d_ws, size_t ws_size,
                              hipStream_t stream) {
  const float* nt  = (const float*)d_in[0];
  const float* nl  = (const float*)d_in[1];
  const float* xe  = (const float*)d_in[2];
  const int*   src = (const int*)d_in[3];
  const int*   dst = (const int*)d_in[4];
  const int*   gid = (const int*)d_in[5];
  const float* Wn0 = (const float*)d_in[6],  *bn0 = (const float*)d_in[7];
  const float* Wv0 = (const float*)d_in[8],  *bv0 = (const float*)d_in[9];
  const float* We0 = (const float*)d_in[10], *be0 = (const float*)d_in[11];
  const float* as0 = (const float*)d_in[12], *ae0 = (const float*)d_in[13];
  const float* ad0 = (const float*)d_in[14], *ab0 = (const float*)d_in[15];
  const float* Wn1 = (const float*)d_in[16], *bn1 = (const float*)d_in[17];
  const float* Wv1 = (const float*)d_in[18], *bv1 = (const float*)d_in[19];
  const float* We1 = (const float*)d_in[20], *be1 = (const float*)d_in[21];
  const float* as1 = (const float*)d_in[22], *ae1 = (const float*)d_in[23];
  const float* ad1 = (const float*)d_in[24], *ab1 = (const float*)d_in[25];
  const float* fcW = (const float*)d_in[26], *fcb = (const float*)d_in[27];
  float* out = (float*)d_out;

  // workspace layout (floats, then uints, then ints); ~152 MB
  float* fold  = (float*)d_ws;                        // 4096
  float* zs    = fold + FOLD_FLOATS;                  // N*2 (layer0 then layer1)
  float* zd    = zs + (size_t)NN*2;                   // N*2
  float* v0    = zd + (size_t)NN*2;                   // N*128
  float* v1    = v0 + (size_t)NN*128;                 // N*128
  float* et1p  = v1 + (size_t)NN*128;                 // E*2
  float* ebuff = et1p + (size_t)EE*2;                 // E*4 (float4 per CSR pos)
  unsigned* menc0 = (unsigned*)(ebuff + (size_t)EE*4); // N*2
  unsigned* menc1 = menc0 + (size_t)NN*2;             // N*2
  float* pnode = (float*)(menc1 + (size_t)NN*2);      // N*2
  int* cnt    = (int*)(pnode + (size_t)NN*2);         // N
  int* off    = cnt + NN;                             // N+1
  int* cursor = off + NN + 1;                         // N
  int* eid    = cursor + NN;                          // E
  int* part   = eid + EE;                             // NCH
  float4* ebuf = (float4*)ebuff;

  hipMemsetAsync(cnt, 0, NN*sizeof(int), stream);
  hipMemsetAsync(menc0, 0, (size_t)NN*4*sizeof(unsigned), stream);  // menc0 + menc1
  fold_k<<<1, 256, 0, stream>>>(Wn0, bn0, as0, ad0, We0, We1, be1, ae1, Wn1, bn1, as1, ad1, fold);
  count_k<<<EE/256, 256, 0, stream>>>(dst, cnt);
  scan1_k<<<NCH, 1024, 0, stream>>>(cnt, part);
  scan2_k<<<1, 1, 0, stream>>>(part, off);
  scan3_k<<<NCH, 1024, 0, stream>>>(cnt, part, off, cursor);
  scatter_k<<<EE/256, 256, 0, stream>>>(dst, cursor, eid);
  node0v_k<<<NN/8, 128, 0, stream>>>(nt, nl, Wv0, bv0, v0);
  nodez_k<<<(NN + 255)/256, 256, 0, stream>>>(nt, nl, fold, zs, zd);
  edge0_k<<<EE/256, 256, 0, stream>>>(xe, src, dst, eid, be0, ae0, ab0, fold, zs, zd, ebuf, et1p, menc0);
  agg0_k<<<NN/16, 256, 0, stream>>>(off, ebuf, menc0, v0, Wv1, bv1, fold, v1, zs, zd);
  edge1_k<<<EE/256, 256, 0, stream>>>(ebuf, zs, zd, et1p, ab1, menc1);
  outinit_k<<<1, 128, 0, stream>>>(fcb, out);
  agg1_k<<<NN/16, 256, 0, stream>>>(off, ebuf, menc1, v1, fcW, pnode);
  gsum_k<<<(NN + 255)/256, 256, 0, stream>>>(pnode, gid, out);
}

// Round 6
// 676.695 us; speedup vs baseline: 3.4082x; 1.1138x over previous
//
#include <hip/hip_runtime.h>

#define NN 100000
#define EE 1600000
#define NG 64
#define NCH 98  // ceil(NN/1024)

// fold-area float offsets
#define OFF_WS0 0
#define OFF_WD0 128
#define OFF_CS0 256
#define OFF_CD0 258
#define OFF_U1  260
#define OFF_C1  324
#define OFF_WS1 512
#define OFF_WD1 768
#define OFF_CS1 1024
#define OFF_CD1 1026
#define OFF_WT0 2048   // transposed We0: [32 out][32 in]
#define FOLD_FLOATS 4096

__device__ __forceinline__ unsigned encm(float f) {
  unsigned u = __float_as_uint(f);
  return (u & 0x80000000u) ? ~u : (u | 0x80000000u);
}
__device__ __forceinline__ float decm(unsigned u) {
  return (u & 0x80000000u) ? __uint_as_float(u & 0x7FFFFFFFu) : __uint_as_float(~u);
}
__device__ __forceinline__ unsigned bf16r(float f) {   // round-to-nearest-even bf16 bits
  unsigned u = __float_as_uint(f);
  return (u + 0x7FFFu + ((u >> 16) & 1u)) >> 16;
}

// ---------------- fold: precompute contracted weight vectors + We0 transpose ----------------
__global__ void fold_k(const float* __restrict__ Wn0, const float* __restrict__ bn0,
                       const float* __restrict__ as0, const float* __restrict__ ad0,
                       const float* __restrict__ We0,
                       const float* __restrict__ We1, const float* __restrict__ be1,
                       const float* __restrict__ ae1,
                       const float* __restrict__ Wn1, const float* __restrict__ bn1,
                       const float* __restrict__ as1, const float* __restrict__ ad1,
                       float* __restrict__ fold) {
  int t = threadIdx.x;  // 256
  for (int i = t; i < 128; i += 256) {        // ws0/wd0: Wn0[2,64,32] . a[2,32]
    int h = i >> 6, d = i & 63;
    float s = 0.f, sd = 0.f;
    for (int k = 0; k < 32; ++k) {
      float w = Wn0[h*2048 + d*32 + k];
      s  += w * as0[h*32 + k];
      sd += w * ad0[h*32 + k];
    }
    fold[OFF_WS0 + i] = s; fold[OFF_WD0 + i] = sd;
  }
  for (int i = t; i < 64; i += 256) {         // u1: We1[2,32,16] . ae1[2,16]
    int h = i >> 5, d = i & 31;
    float s = 0.f;
    for (int k = 0; k < 16; ++k) s += We1[h*512 + d*16 + k] * ae1[h*16 + k];
    fold[OFF_U1 + i] = s;
  }
  for (int i = t; i < 1024; i += 256) {       // WT0[o][d] = We0[o>>4][d][o&15]
    int o = i >> 5, d = i & 31;
    fold[OFF_WT0 + o*32 + d] = We0[(o >> 4)*512 + d*16 + (o & 15)];
  }
  if (t < 256) {                              // ws1/wd1: Wn1[2,128,32] . a[2,32]
    int i = t, h = i >> 7, d = i & 127;
    float s = 0.f, sd = 0.f;
    for (int k = 0; k < 32; ++k) {
      float w = Wn1[h*4096 + d*32 + k];
      s  += w * as1[h*32 + k];
      sd += w * ad1[h*32 + k];
    }
    fold[OFF_WS1 + i] = s; fold[OFF_WD1 + i] = sd;
  }
  if (t < 2) {
    float cs = 0.f, cd = 0.f;
    for (int k = 0; k < 32; ++k) { cs += bn0[t*32+k]*as0[t*32+k]; cd += bn0[t*32+k]*ad0[t*32+k]; }
    fold[OFF_CS0 + t] = cs; fold[OFF_CD0 + t] = cd;
    float c1 = 0.f;
    for (int k = 0; k < 16; ++k) c1 += ae1[t*16+k]*be1[t*16+k];
    fold[OFF_C1 + t] = c1;
    float cs1 = 0.f, cd1 = 0.f;
    for (int k = 0; k < 32; ++k) { cs1 += bn1[t*32+k]*as1[t*32+k]; cd1 += bn1[t*32+k]*ad1[t*32+k]; }
    fold[OFF_CS1 + t] = cs1; fold[OFF_CD1 + t] = cd1;
  }
}

// ---------------- CSR build ----------------
__global__ void count_k(const int* __restrict__ dst, int* __restrict__ cnt) {
  int e = blockIdx.x*256 + threadIdx.x;
  if (e < EE) atomicAdd(&cnt[dst[e]], 1);
}

__global__ __launch_bounds__(1024) void scan1_k(const int* __restrict__ cnt, int* __restrict__ partial) {
  int tid = threadIdx.x, lane = tid & 63, w = tid >> 6;
  int i = blockIdx.x*1024 + tid;
  int v = (i < NN) ? cnt[i] : 0;
  #pragma unroll
  for (int d = 32; d > 0; d >>= 1) v += __shfl_down(v, d);
  __shared__ int wsum[16];
  if (lane == 0) wsum[w] = v;
  __syncthreads();
  if (tid == 0) { int s = 0; for (int q = 0; q < 16; ++q) s += wsum[q]; partial[blockIdx.x] = s; }
}

__global__ void scan2_k(int* __restrict__ partial, int* __restrict__ off) {  // <<<1,1>>>
  int s = 0;
  for (int b = 0; b < NCH; ++b) { int t = partial[b]; partial[b] = s; s += t; }
  off[NN] = s;
}

__global__ __launch_bounds__(1024) void scan3_k(const int* __restrict__ cnt, const int* __restrict__ pbase,
                                                int* __restrict__ off, int* __restrict__ cursor) {
  int tid = threadIdx.x, lane = tid & 63, w = tid >> 6;
  int i = blockIdx.x*1024 + tid;
  int v = (i < NN) ? cnt[i] : 0;
  int x = v;
  #pragma unroll
  for (int d = 1; d < 64; d <<= 1) { int t = __shfl_up(x, d); if (lane >= d) x += t; }
  __shared__ int wsum[16], wbase[16];
  if (lane == 63) wsum[w] = x;
  __syncthreads();
  if (tid == 0) { int s = 0; for (int q = 0; q < 16; ++q) { wbase[q] = s; s += wsum[q]; } }
  __syncthreads();
  int excl = pbase[blockIdx.x] + wbase[w] + x - v;
  if (i < NN) { off[i] = excl; cursor[i] = excl; }
}

__global__ void scatter_k(const int* __restrict__ dst, int* __restrict__ cursor, int* __restrict__ eid) {
  int e = blockIdx.x*256 + threadIdx.x;
  if (e < EE) { int p = atomicAdd(&cursor[dst[e]], 1); eid[p] = e; }
}

// ---------------- layer-0 v-projection: W in VGPRs, 8 nodes/block, bf16 packed output ----------------
__global__ __launch_bounds__(128) void node0v_k(const float* __restrict__ nt, const float* __restrict__ nl,
                                                const float* __restrict__ Wv0, const float* __restrict__ bv0,
                                                unsigned* __restrict__ v0b) {
  int tid = threadIdx.x;
  int h = tid >> 6, k = tid & 63;
  int sl2 = k & 31;
  float w[64];
  #pragma unroll
  for (int d = 0; d < 64; ++d) w[d] = Wv0[h*4096 + d*64 + k];
  float b = bv0[tid];
  int nb = blockIdx.x * 8;   // grid 12500 * 8 = 100000 exactly
  #pragma unroll 1
  for (int r = 0; r < 8; ++r) {
    int n = nb + r;
    const float* nrow = nt + (size_t)n*14;   // uniform addresses -> SGPR loads
    const float* lrow = nl + (size_t)n*50;
    float acc = b;
    #pragma unroll
    for (int d = 0; d < 14; ++d) acc = fmaf(nrow[d], w[d], acc);
    #pragma unroll
    for (int d = 0; d < 50; ++d) acc = fmaf(lrow[d], w[14 + d], acc);
    float p0 = __shfl(acc, 2*sl2);
    float p1 = __shfl(acc, 2*sl2 + 1);
    if (k < 32) v0b[(size_t)n*64 + h*32 + sl2] = bf16r(p0) | (bf16r(p1) << 16);
  }
}

// ---------------- layer-0 z-scalars: one thread per node ----------------
__global__ __launch_bounds__(256) void nodez_k(const float* __restrict__ nt, const float* __restrict__ nl,
                                               const float* __restrict__ fold,
                                               float* __restrict__ zs0, float* __restrict__ zd0) {
  int n = blockIdx.x*256 + threadIdx.x;
  if (n >= NN) return;
  float p0 = 0.f, p1 = 0.f, p2 = 0.f, p3 = 0.f;
  #pragma unroll
  for (int d = 0; d < 64; ++d) {
    float x = (d < 14) ? nt[(size_t)n*14 + d] : nl[(size_t)n*50 + d - 14];
    p0 = fmaf(x, fold[OFF_WS0 + d],      p0);
    p1 = fmaf(x, fold[OFF_WS0 + 64 + d], p1);
    p2 = fmaf(x, fold[OFF_WD0 + d],      p2);
    p3 = fmaf(x, fold[OFF_WD0 + 64 + d], p3);
  }
  zs0[n*2]   = p0 + fold[OFF_CS0];
  zs0[n*2+1] = p1 + fold[OFF_CS0+1];
  zd0[n*2]   = p2 + fold[OFF_CD0];
  zd0[n*2+1] = p3 + fold[OFF_CD0+1];
}

// ---------------- layer-0 edge pass (CSR order): uniform-W MLP, coalesced writes, segmented max ----------------
__global__ __launch_bounds__(256) void edge0_k(const float* __restrict__ xe,
                                               const int* __restrict__ src, const int* __restrict__ dst,
                                               const int* __restrict__ eid,
                                               const float* __restrict__ be0,
                                               const float* __restrict__ ae0, const float* __restrict__ ab0,
                                               const float* __restrict__ fold,
                                               const float* __restrict__ zs0, const float* __restrict__ zd0,
                                               float4* __restrict__ ebuf, float* __restrict__ et1p,
                                               unsigned* __restrict__ menc0) {
  int p = blockIdx.x*256 + threadIdx.x;   // grid exact: EE/256
  int lane = threadIdx.x & 63;
  int e = eid[p];
  int sn = src[e], dn = dst[e];
  const float4* xp = reinterpret_cast<const float4*>(xe + (size_t)e*32);
  float4 xv[8];
  #pragma unroll
  for (int q = 0; q < 8; ++q) xv[q] = xp[q];
  const float* WT = fold + OFF_WT0;
  const float* U1 = fold + OFF_U1;
  float s0 = 0.f, s1 = 0.f, etA = 0.f, etB = 0.f;
  #pragma unroll 4
  for (int o = 0; o < 16; ++o) {          // head 0
    float acc = be0[o];
    #pragma unroll
    for (int q = 0; q < 8; ++q) {         // WT row: wave-uniform -> SGPR loads
      float4 w = *reinterpret_cast<const float4*>(WT + o*32 + q*4);
      acc = fmaf(xv[q].x, w.x, acc); acc = fmaf(xv[q].y, w.y, acc);
      acc = fmaf(xv[q].z, w.z, acc); acc = fmaf(xv[q].w, w.w, acc);
    }
    s0 = fmaf(ae0[o], acc, s0);
    float lz = acc >= 0.f ? acc : 0.01f*acc;
    etA = fmaf(lz, U1[o], etA); etB = fmaf(lz, U1[32 + o], etB);
  }
  #pragma unroll 4
  for (int o = 16; o < 32; ++o) {         // head 1
    float acc = be0[o];
    #pragma unroll
    for (int q = 0; q < 8; ++q) {
      float4 w = *reinterpret_cast<const float4*>(WT + o*32 + q*4);
      acc = fmaf(xv[q].x, w.x, acc); acc = fmaf(xv[q].y, w.y, acc);
      acc = fmaf(xv[q].z, w.z, acc); acc = fmaf(xv[q].w, w.w, acc);
    }
    s1 = fmaf(ae0[o], acc, s1);
    float lz = acc >= 0.f ? acc : 0.01f*acc;
    etA = fmaf(lz, U1[o], etA); etB = fmaf(lz, U1[32 + o], etB);
  }
  float2 zsv = *reinterpret_cast<const float2*>(zs0 + (size_t)sn*2);
  float2 zdv = *reinterpret_cast<const float2*>(zd0 + (size_t)dn*2);
  float l0 = zsv.x + s0 + zdv.x + ab0[0];
  float l1 = zsv.y + s1 + zdv.y + ab0[1];
  l0 = l0 >= 0.f ? l0 : 0.2f*l0;
  l1 = l1 >= 0.f ? l1 : 0.2f*l1;
  ebuf[p] = make_float4(__int_as_float(sn), l0, l1, __int_as_float(dn));
  *reinterpret_cast<float2*>(et1p + (size_t)p*2) =
      make_float2(etA + fold[OFF_C1], etB + fold[OFF_C1+1]);
  // segmented max over sorted dn
  unsigned e0 = encm(l0), e1 = encm(l1);
  #pragma unroll
  for (int o = 1; o < 64; o <<= 1) {      // max idempotent: wave-edge self-return safe
    int pdn = __shfl_down(dn, o);
    unsigned q0 = __shfl_down(e0, o);
    unsigned q1 = __shfl_down(e1, o);
    if (pdn == dn) { e0 = max(e0, q0); e1 = max(e1, q1); }
  }
  int prev = __shfl_up(dn, 1);
  if (lane == 0 || prev != dn) {
    atomicMax(&menc0[(size_t)dn*2],   e0);
    atomicMax(&menc0[(size_t)dn*2+1], e1);
  }
}

// ---------------- layer-0 aggregate: quad-edge bf16 gathers, 4 nodes/wave, fused l1 node MLP ----------------
__global__ __launch_bounds__(256) void agg0_k(const int* __restrict__ off,
                                              const float4* __restrict__ ebuf,
                                              const unsigned* __restrict__ menc,
                                              const unsigned short* __restrict__ v0b,
                                              const float* __restrict__ Wv1, const float* __restrict__ bv1,
                                              const float* __restrict__ fold,
                                              unsigned* __restrict__ v1b, float* __restrict__ zs1, float* __restrict__ zd1) {
  int tid = threadIdx.x, w = tid >> 6, lane = tid & 63;
  int sl = lane & 15, qt = lane >> 4;    // 16-lane quarter covers one 256B bf16 row
  int base = blockIdx.x*16 + w*4;        // grid 6250 * 16 nodes = 100000 exactly
  __shared__ float xsh[16][128];
  #pragma unroll 1
  for (int k = 0; k < 4; ++k) {
    int n = base + k;
    int st = off[n], en = off[n+1];
    float m = (sl < 8) ? decm(menc[n*2]) : decm(menc[n*2+1]);
    float ac0=0.f, ac1=0.f, ac2=0.f, ac3=0.f, ac4=0.f, ac5=0.f, ac6=0.f, ac7=0.f, den=0.f;
    for (int i = st; i < en; i += 16) {
      float4 eb[4];
      #pragma unroll
      for (int qq = 0; qq < 4; ++qq) { int j = i + qq*4 + qt; eb[qq] = ebuf[(j < en) ? j : st]; }
      #pragma unroll
      for (int qq = 0; qq < 4; ++qq) {
        int sn = __float_as_int(eb[qq].x);
        uint4 vv = *reinterpret_cast<const uint4*>(v0b + (size_t)sn*128 + sl*8);
        bool okq = (i + qq*4 + qt) < en;
        float s = (sl < 8) ? eb[qq].y : eb[qq].z;
        float e = okq ? __expf(s - m) : 0.f;
        den += e;
        ac0 = fmaf(e, __uint_as_float(vv.x << 16),          ac0);
        ac1 = fmaf(e, __uint_as_float(vv.x & 0xFFFF0000u),  ac1);
        ac2 = fmaf(e, __uint_as_float(vv.y << 16),          ac2);
        ac3 = fmaf(e, __uint_as_float(vv.y & 0xFFFF0000u),  ac3);
        ac4 = fmaf(e, __uint_as_float(vv.z << 16),          ac4);
        ac5 = fmaf(e, __uint_as_float(vv.z & 0xFFFF0000u),  ac5);
        ac6 = fmaf(e, __uint_as_float(vv.w << 16),          ac6);
        ac7 = fmaf(e, __uint_as_float(vv.w & 0xFFFF0000u),  ac7);
      }
    }
    #pragma unroll
    for (int o = 16; o <= 32; o <<= 1) {
      ac0 += __shfl_xor(ac0, o); ac1 += __shfl_xor(ac1, o);
      ac2 += __shfl_xor(ac2, o); ac3 += __shfl_xor(ac3, o);
      ac4 += __shfl_xor(ac4, o); ac5 += __shfl_xor(ac5, o);
      ac6 += __shfl_xor(ac6, o); ac7 += __shfl_xor(ac7, o);
      den += __shfl_xor(den, o);
    }
    float inv = 1.f / (den + 1e-9f);
    float x0 = ac0*inv, x1 = ac1*inv, x2 = ac2*inv, x3 = ac3*inv;
    float x4 = ac4*inv, x5 = ac5*inv, x6 = ac6*inv, x7 = ac7*inv;
    x0 = x0 >= 0.f ? x0 : 0.01f*x0;  x1 = x1 >= 0.f ? x1 : 0.01f*x1;   // inter-layer leaky
    x2 = x2 >= 0.f ? x2 : 0.01f*x2;  x3 = x3 >= 0.f ? x3 : 0.01f*x3;
    x4 = x4 >= 0.f ? x4 : 0.01f*x4;  x5 = x5 >= 0.f ? x5 : 0.01f*x5;
    x6 = x6 >= 0.f ? x6 : 0.01f*x6;  x7 = x7 >= 0.f ? x7 : 0.01f*x7;
    if (lane < 16) {
      *reinterpret_cast<float4*>(&xsh[w*4 + k][sl*8])     = make_float4(x0, x1, x2, x3);
      *reinterpret_cast<float4*>(&xsh[w*4 + k][sl*8 + 4]) = make_float4(x4, x5, x6, x7);
    }
  }
  __syncthreads();
  // ---- layer-1 node MLP for the wave's 4 nodes (Wv1 read once per 4 nodes) ----
  float bA = bv1[lane], bB = bv1[64 + lane];
  float a[4] = {bA, bA, bA, bA};
  float b[4] = {bB, bB, bB, bB};
  const float* xr0 = xsh[w*4 + 0];
  const float* xr1 = xsh[w*4 + 1];
  const float* xr2 = xsh[w*4 + 2];
  const float* xr3 = xsh[w*4 + 3];
  #pragma unroll 4
  for (int d4 = 0; d4 < 32; ++d4) {
    float4 xv0 = *reinterpret_cast<const float4*>(xr0 + d4*4);
    float4 xv1 = *reinterpret_cast<const float4*>(xr1 + d4*4);
    float4 xv2 = *reinterpret_cast<const float4*>(xr2 + d4*4);
    float4 xv3 = *reinterpret_cast<const float4*>(xr3 + d4*4);
    #pragma unroll
    for (int c = 0; c < 4; ++c) {
      int d = d4*4 + c;
      float w0 = Wv1[d*64 + lane];
      float w1 = Wv1[8192 + d*64 + lane];
      float q0 = (c == 0) ? xv0.x : (c == 1) ? xv0.y : (c == 2) ? xv0.z : xv0.w;
      float q1 = (c == 0) ? xv1.x : (c == 1) ? xv1.y : (c == 2) ? xv1.z : xv1.w;
      float q2 = (c == 0) ? xv2.x : (c == 1) ? xv2.y : (c == 2) ? xv2.z : xv2.w;
      float q3 = (c == 0) ? xv3.x : (c == 1) ? xv3.y : (c == 2) ? xv3.z : xv3.w;
      a[0] = fmaf(q0, w0, a[0]); b[0] = fmaf(q0, w1, b[0]);
      a[1] = fmaf(q1, w0, a[1]); b[1] = fmaf(q1, w1, b[1]);
      a[2] = fmaf(q2, w0, a[2]); b[2] = fmaf(q2, w1, b[2]);
      a[3] = fmaf(q3, w0, a[3]); b[3] = fmaf(q3, w1, b[3]);
    }
  }
  // pack v1 rows to bf16: word l covers dims 2l,2l+1 (a-range for l<32, b-range for l>=32)
  {
    int s2 = (2*lane) & 63;
    #pragma unroll
    for (int k = 0; k < 4; ++k) {
      float pa0 = __shfl(a[k], s2), pa1 = __shfl(a[k], s2 + 1);
      float pb0 = __shfl(b[k], s2), pb1 = __shfl(b[k], s2 + 1);
      float lo = (lane < 32) ? pa0 : pb0;
      float hi = (lane < 32) ? pa1 : pb1;
      v1b[(size_t)(base + k)*64 + lane] = bf16r(lo) | (bf16r(hi) << 16);
    }
  }
  // ---- zs1/zd1 scalars per node ----
  #pragma unroll 1
  for (int k = 0; k < 4; ++k) {
    int n = base + k;
    float xl = xsh[w*4 + k][lane], xh = xsh[w*4 + k][64 + lane];
    float p0 = xl*fold[OFF_WS1 + lane]       + xh*fold[OFF_WS1 + 64 + lane];
    float p1 = xl*fold[OFF_WS1 + 128 + lane] + xh*fold[OFF_WS1 + 192 + lane];
    float p2 = xl*fold[OFF_WD1 + lane]       + xh*fold[OFF_WD1 + 64 + lane];
    float p3 = xl*fold[OFF_WD1 + 128 + lane] + xh*fold[OFF_WD1 + 192 + lane];
    #pragma unroll
    for (int o = 32; o > 0; o >>= 1) {
      p0 += __shfl_down(p0, o); p1 += __shfl_down(p1, o);
      p2 += __shfl_down(p2, o); p3 += __shfl_down(p3, o);
    }
    if (lane == 0) {
      zs1[n*2]   = p0 + fold[OFF_CS1];
      zs1[n*2+1] = p1 + fold[OFF_CS1+1];
      zd1[n*2]   = p2 + fold[OFF_CD1];
      zd1[n*2+1] = p3 + fold[OFF_CD1+1];
    }
  }
}

// ---------------- layer-1 edge logits + fused segmented max (dn from ebuf.w, sorted) ----------------
__global__ __launch_bounds__(256) void edge1_k(float4* __restrict__ ebuf,
                                               const float* __restrict__ zs1, const float* __restrict__ zd1,
                                               const float* __restrict__ et1p, const float* __restrict__ ab1,
                                               unsigned* __restrict__ menc1) {
  int i = blockIdx.x*256 + threadIdx.x;
  int lane = threadIdx.x & 63;
  bool ok = i < EE;
  float l0 = 0.f, l1 = 0.f; int dn = -1;
  if (ok) {
    float4 eb = ebuf[i];
    int sn = __float_as_int(eb.x);
    dn = __float_as_int(eb.w);
    float2 et = *reinterpret_cast<const float2*>(et1p + (size_t)i*2);
    l0 = zs1[sn*2]   + et.x + zd1[dn*2]   + ab1[0];
    l1 = zs1[sn*2+1] + et.y + zd1[dn*2+1] + ab1[1];
    l0 = l0 >= 0.f ? l0 : 0.2f*l0;
    l1 = l1 >= 0.f ? l1 : 0.2f*l1;
    eb.y = l0; eb.z = l1;
    ebuf[i] = eb;
  }
  unsigned e0 = ok ? encm(l0) : 0u;
  unsigned e1 = ok ? encm(l1) : 0u;
  #pragma unroll
  for (int o = 1; o < 64; o <<= 1) {   // max is idempotent: shfl self-return at wave edge is safe
    int pdn = __shfl_down(dn, o);
    unsigned q0 = __shfl_down(e0, o);
    unsigned q1 = __shfl_down(e1, o);
    if (pdn == dn) { e0 = max(e0, q0); e1 = max(e1, q1); }
  }
  int prev = __shfl_up(dn, 1);
  if (ok && (lane == 0 || prev != dn)) {
    atomicMax(&menc1[(size_t)dn*2],   e0);
    atomicMax(&menc1[(size_t)dn*2+1], e1);
  }
}

__global__ void outinit_k(const float* __restrict__ fcb, float* __restrict__ out) {
  int i = threadIdx.x;  // 128
  out[i] = fcb[i & 1];
}

// ---------------- layer-1 aggregate: quad-edge bf16 gathers, 4 nodes/wave, fused FC ----------------
__global__ __launch_bounds__(256) void agg1_k(const int* __restrict__ off,
                                              const float4* __restrict__ ebuf,
                                              const unsigned* __restrict__ menc,
                                              const unsigned short* __restrict__ v1b,
                                              const float* __restrict__ fcW,
                                              float* __restrict__ pnode) {
  int tid = threadIdx.x, w = tid >> 6, lane = tid & 63;
  int sl = lane & 15, qt = lane >> 4;
  int base = blockIdx.x*16 + w*4;
  // fcW rows for this lane's 8 dims: fw[c2] covers dims sl*8+2c2, sl*8+2c2+1 (p0,p1 interleaved)
  const float4* fw4 = reinterpret_cast<const float4*>(fcW);
  float4 fw[4];
  #pragma unroll
  for (int c2 = 0; c2 < 4; ++c2) fw[c2] = fw4[sl*4 + c2];
  #pragma unroll 1
  for (int k = 0; k < 4; ++k) {
    int n = base + k;
    int st = off[n], en = off[n+1];
    float m = (sl < 8) ? decm(menc[n*2]) : decm(menc[n*2+1]);
    float ac0=0.f, ac1=0.f, ac2=0.f, ac3=0.f, ac4=0.f, ac5=0.f, ac6=0.f, ac7=0.f, den=0.f;
    for (int i = st; i < en; i += 16) {
      float4 eb[4];
      #pragma unroll
      for (int qq = 0; qq < 4; ++qq) { int j = i + qq*4 + qt; eb[qq] = ebuf[(j < en) ? j : st]; }
      #pragma unroll
      for (int qq = 0; qq < 4; ++qq) {
        int sn = __float_as_int(eb[qq].x);
        uint4 vv = *reinterpret_cast<const uint4*>(v1b + (size_t)sn*128 + sl*8);
        bool okq = (i + qq*4 + qt) < en;
        float s = (sl < 8) ? eb[qq].y : eb[qq].z;
        float e = okq ? __expf(s - m) : 0.f;
        den += e;
        ac0 = fmaf(e, __uint_as_float(vv.x << 16),          ac0);
        ac1 = fmaf(e, __uint_as_float(vv.x & 0xFFFF0000u),  ac1);
        ac2 = fmaf(e, __uint_as_float(vv.y << 16),          ac2);
        ac3 = fmaf(e, __uint_as_float(vv.y & 0xFFFF0000u),  ac3);
        ac4 = fmaf(e, __uint_as_float(vv.z << 16),          ac4);
        ac5 = fmaf(e, __uint_as_float(vv.z & 0xFFFF0000u),  ac5);
        ac6 = fmaf(e, __uint_as_float(vv.w << 16),          ac6);
        ac7 = fmaf(e, __uint_as_float(vv.w & 0xFFFF0000u),  ac7);
      }
    }
    #pragma unroll
    for (int o = 16; o <= 32; o <<= 1) {
      ac0 += __shfl_xor(ac0, o); ac1 += __shfl_xor(ac1, o);
      ac2 += __shfl_xor(ac2, o); ac3 += __shfl_xor(ac3, o);
      ac4 += __shfl_xor(ac4, o); ac5 += __shfl_xor(ac5, o);
      ac6 += __shfl_xor(ac6, o); ac7 += __shfl_xor(ac7, o);
      den += __shfl_xor(den, o);
    }
    float inv = 1.f / (den + 1e-9f);          // final layer: NO leaky
    float h0 = ac0*inv, h1 = ac1*inv, h2 = ac2*inv, h3 = ac3*inv;
    float h4 = ac4*inv, h5 = ac5*inv, h6 = ac6*inv, h7 = ac7*inv;
    float p0 = h0*fw[0].x + h1*fw[0].z + h2*fw[1].x + h3*fw[1].z
             + h4*fw[2].x + h5*fw[2].z + h6*fw[3].x + h7*fw[3].z;
    float p1 = h0*fw[0].y + h1*fw[0].w + h2*fw[1].y + h3*fw[1].w
             + h4*fw[2].y + h5*fw[2].w + h6*fw[3].y + h7*fw[3].w;
    #pragma unroll
    for (int o = 8; o > 0; o >>= 1) {   // xor stays within 16-lane quarter; quarters replicate
      p0 += __shfl_xor(p0, o);
      p1 += __shfl_xor(p1, o);
    }
    if (lane == 0) {
      pnode[n*2]   = p0;
      pnode[n*2+1] = p1;
    }
  }
}

// ---------------- graph readout: segmented sum over sorted gid, few atomics ----------------
__global__ __launch_bounds__(256) void gsum_k(const float* __restrict__ pnode, const int* __restrict__ gid,
                                              float* __restrict__ out) {
  int n = blockIdx.x*256 + threadIdx.x;
  int lane = threadIdx.x & 63;
  bool ok = n < NN;
  int g = ok ? gid[n] : -1;
  float p0 = ok ? pnode[n*2]   : 0.f;
  float p1 = ok ? pnode[n*2+1] : 0.f;
  #pragma unroll
  for (int o = 1; o < 64; o <<= 1) {
    int pg = __shfl_down(g, o);
    float q0 = __shfl_down(p0, o);
    float q1 = __shfl_down(p1, o);
    if ((lane + o) < 64 && pg == g) { p0 += q0; p1 += q1; }  // clamp: sum is NOT idempotent
  }
  int prev = __shfl_up(g, 1);
  if (ok && (lane == 0 || prev != g)) {
    atomicAdd(&out[g*2],     p0);
    atomicAdd(&out[g*2 + 1], p1);
  }
}

extern "C" void kernel_launch(void* const* d_in, const int* in_sizes, int n_in,
                              void* d_out, int out_size, void* d_ws, size_t ws_size,
                              hipStream_t stream) {
  const float* nt  = (const float*)d_in[0];
  const float* nl  = (const float*)d_in[1];
  const float* xe  = (const float*)d_in[2];
  const int*   src = (const int*)d_in[3];
  const int*   dst = (const int*)d_in[4];
  const int*   gid = (const int*)d_in[5];
  const float* Wn0 = (const float*)d_in[6],  *bn0 = (const float*)d_in[7];
  const float* Wv0 = (const float*)d_in[8],  *bv0 = (const float*)d_in[9];
  const float* We0 = (const float*)d_in[10], *be0 = (const float*)d_in[11];
  const float* as0 = (const float*)d_in[12], *ae0 = (const float*)d_in[13];
  const float* ad0 = (const float*)d_in[14], *ab0 = (const float*)d_in[15];
  const float* Wn1 = (const float*)d_in[16], *bn1 = (const float*)d_in[17];
  const float* Wv1 = (const float*)d_in[18], *bv1 = (const float*)d_in[19];
  const float* We1 = (const float*)d_in[20], *be1 = (const float*)d_in[21];
  const float* as1 = (const float*)d_in[22], *ae1 = (const float*)d_in[23];
  const float* ad1 = (const float*)d_in[24], *ab1 = (const float*)d_in[25];
  const float* fcW = (const float*)d_in[26], *fcb = (const float*)d_in[27];
  float* out = (float*)d_out;

  // workspace layout (floats, then uints, then ints); ~90 MB
  float* fold  = (float*)d_ws;                        // 4096
  float* zs    = fold + FOLD_FLOATS;                  // N*2 (layer0 then layer1)
  float* zd    = zs + (size_t)NN*2;                   // N*2
  unsigned* v0b = (unsigned*)(zd + (size_t)NN*2);     // N*64 u32 (bf16 x2)
  unsigned* v1b = v0b + (size_t)NN*64;                // N*64 u32
  float* et1p  = (float*)(v1b + (size_t)NN*64);       // E*2
  float* ebuff = et1p + (size_t)EE*2;                 // E*4 (float4 per CSR pos)
  unsigned* menc0 = (unsigned*)(ebuff + (size_t)EE*4); // N*2
  unsigned* menc1 = menc0 + (size_t)NN*2;             // N*2
  float* pnode = (float*)(menc1 + (size_t)NN*2);      // N*2
  int* cnt    = (int*)(pnode + (size_t)NN*2);         // N
  int* off    = cnt + NN;                             // N+1
  int* cursor = off + NN + 1;                         // N
  int* eid    = cursor + NN;                          // E
  int* part   = eid + EE;                             // NCH
  float4* ebuf = (float4*)ebuff;

  hipMemsetAsync(cnt, 0, NN*sizeof(int), stream);
  hipMemsetAsync(menc0, 0, (size_t)NN*4*sizeof(unsigned), stream);  // menc0 + menc1
  fold_k<<<1, 256, 0, stream>>>(Wn0, bn0, as0, ad0, We0, We1, be1, ae1, Wn1, bn1, as1, ad1, fold);
  count_k<<<EE/256, 256, 0, stream>>>(dst, cnt);
  scan1_k<<<NCH, 1024, 0, stream>>>(cnt, part);
  scan2_k<<<1, 1, 0, stream>>>(part, off);
  scan3_k<<<NCH, 1024, 0, stream>>>(cnt, part, off, cursor);
  scatter_k<<<EE/256, 256, 0, stream>>>(dst, cursor, eid);
  node0v_k<<<NN/8, 128, 0, stream>>>(nt, nl, Wv0, bv0, v0b);
  nodez_k<<<(NN + 255)/256, 256, 0, stream>>>(nt, nl, fold, zs, zd);
  edge0_k<<<EE/256, 256, 0, stream>>>(xe, src, dst, eid, be0, ae0, ab0, fold, zs, zd, ebuf, et1p, menc0);
  agg0_k<<<NN/16, 256, 0, stream>>>(off, ebuf, menc0, (const unsigned short*)v0b, Wv1, bv1, fold, v1b, zs, zd);
  edge1_k<<<EE/256, 256, 0, stream>>>(ebuf, zs, zd, et1p, ab1, menc1);
  outinit_k<<<1, 128, 0, stream>>>(fcb, out);
  agg1_k<<<NN/16, 256, 0, stream>>>(off, ebuf, menc1, (const unsigned short*)v1b, fcW, pnode);
  gsum_k<<<(NN + 255)/256, 256, 0, stream>>>(pnode, gid, out);
}